// Round 4
// baseline (237.676 us; speedup 1.0000x reference)
//
#include <hip/hip_runtime.h>
#include <hip/hip_bf16.h>

// B=4, L=2048, D=1024, H=16, HD=64, K=32, MAXLEN=2048
#define LL 2048

typedef __bf16 bf16x8 __attribute__((ext_vector_type(8)));
typedef __bf16 bf16x4 __attribute__((ext_vector_type(4)));
typedef float f32x4 __attribute__((ext_vector_type(4)));

// async global->LDS, 16B per lane; LDS dest = wave-uniform base + lane*16
__device__ inline void gl_lds16(const __bf16* g, __bf16* l) {
    __builtin_amdgcn_global_load_lds((const __attribute__((address_space(1))) void*)g,
                                     (__attribute__((address_space(3))) void*)l, 16, 0, 0);
}

// ---------------------------------------------------------------------------
// Unified prep: blocks [0,4096) cast inputs_kv->A1; [4096,4608) cast r1->r1b;
// [4608,5120) transpose Wv; [5120,5632) transpose Wo; [5632,6144) transpose r2.
// ---------------------------------------------------------------------------
__global__ __launch_bounds__(256) void prep(const float* __restrict__ inputs_kv,
                                            const float* __restrict__ r1,
                                            const float* __restrict__ Wv,
                                            const float* __restrict__ Wo,
                                            const float* __restrict__ r2,
                                            __bf16* __restrict__ A1,
                                            __bf16* __restrict__ r1b,
                                            __bf16* __restrict__ Wvt,
                                            __bf16* __restrict__ Wot,
                                            __bf16* __restrict__ r2t) {
    __shared__ float Ls[32][65];
    int bid = blockIdx.x;
    const int tid = threadIdx.x;
    if (bid < 4608) {
        const float* in = (bid < 4096) ? inputs_kv : r1;
        __bf16* out = (bid < 4096) ? A1 : r1b;
        const int t = ((bid < 4096) ? bid : bid - 4096) * 256 + tid;
        const float4* in4 = (const float4*)in;
        float4 f0 = in4[t * 2], f1 = in4[t * 2 + 1];
        bf16x8 o;
        o[0] = (__bf16)f0.x; o[1] = (__bf16)f0.y; o[2] = (__bf16)f0.z; o[3] = (__bf16)f0.w;
        o[4] = (__bf16)f1.x; o[5] = (__bf16)f1.y; o[6] = (__bf16)f1.z; o[7] = (__bf16)f1.w;
        *(bf16x8*)&out[(size_t)t * 8] = o;
        return;
    }
    bid -= 4608;
    const float* in;
    __bf16* out;
    int R, C, r0, c0;
    if (bid < 512) {
        in = Wv; out = Wvt; R = 1024; C = 1024;
        c0 = (bid & 15) * 64; r0 = (bid >> 4) * 32;
    } else if (bid < 1024) {
        bid -= 512;
        in = Wo; out = Wot; R = 1024; C = 1024;
        c0 = (bid & 15) * 64; r0 = (bid >> 4) * 32;
    } else {
        bid -= 1024;
        const int bz = bid >> 5;
        in = r2 + (size_t)bz * 65536; out = r2t + (size_t)bz * 65536;
        R = 32; C = 2048;
        c0 = (bid & 31) * 64; r0 = 0;
    }
#pragma unroll
    for (int p = 0; p < 2; ++p) {
        int f = tid + 256 * p;
        int row = f >> 4, c4 = (f & 15) << 2;
        float4 v = *(const float4*)&in[(size_t)(r0 + row) * C + c0 + c4];
        Ls[row][c4 + 0] = v.x; Ls[row][c4 + 1] = v.y;
        Ls[row][c4 + 2] = v.z; Ls[row][c4 + 3] = v.w;
    }
    __syncthreads();
    const int orow = tid >> 2, rc = (tid & 3) << 3;
    bf16x8 o;
#pragma unroll
    for (int j = 0; j < 8; ++j) o[j] = (__bf16)Ls[rc + j][orow];
    *(bf16x8*)&out[(size_t)(c0 + orow) * R + r0 + rc] = o;
}

// ---------------------------------------------------------------------------
// bf16 MFMA GEMM, T3-minimal 2-phase: double-buffered LDS, stage(t+1) issued
// BEFORE compute(t), ONE __syncthreads per K-step (drains vmcnt+lgkm: stage
// loads of buf[nxt] land while MFMAs read buf[cur]).  Old structure was
// sync;stage;sync;compute = zero overlap, 2 barriers/step — fine at m97's
// 3-4 blocks/CU, not at our grid-limited 2 blocks/CU.
// XCD-chunked tile swizzle (T1): per-XCD working set 2MB A-slice + 2MB B.
// MODE 0: scatter bf16 V into FRAGMENT-MAJOR layout V3 (see attn).
// MODE 1: write fp32 C[row][col]
// ---------------------------------------------------------------------------
template <int MODE>
__global__ __launch_bounds__(256) void gemm_bt(const __bf16* __restrict__ A,
                                               const __bf16* __restrict__ Bt,
                                               const float* __restrict__ bias,
                                               void* __restrict__ Cout,
                                               int M, int N, int K) {
    __shared__ alignas(16) __bf16 As[2][128 * 32];
    __shared__ alignas(16) __bf16 Bs[2][128 * 32];
    const int tid = threadIdx.x;
    const int lane = tid & 63;
    const int wid = __builtin_amdgcn_readfirstlane(tid >> 6);
    // XCD-chunked swizzle: grid is (8,64) -> 512 flat ids
    const int f = blockIdx.y * 8 + blockIdx.x;
    const int g = (f & 7) * 64 + (f >> 3);
    const int row0 = (g >> 3) * 128, col0 = (g & 7) * 128;
    const int l15 = lane & 15, quad = lane >> 4;
    const int wr = wid & 1, wc = wid >> 1;
    const int s0 = wid * 2, s1 = s0 + 1;

    const __bf16* ga0 = A + (size_t)(row0 + s0 * 16 + (lane >> 2)) * K + ((lane & 3) << 3);
    const __bf16* ga1 = ga0 + (size_t)16 * K;
    const __bf16* gb0 = Bt + (size_t)(col0 + s0 * 16 + (lane >> 2)) * K + ((lane & 3) << 3);
    const __bf16* gb1 = gb0 + (size_t)16 * K;

    f32x4 acc[4][4];
#pragma unroll
    for (int i = 0; i < 4; ++i)
#pragma unroll
        for (int j = 0; j < 4; ++j) acc[i][j] = (f32x4){0.f, 0.f, 0.f, 0.f};

    const int nt = K >> 5;  // K-steps of 32
    // prologue: stage tile 0 into buf 0
    gl_lds16(ga0, As[0] + s0 * 512);
    gl_lds16(ga1, As[0] + s1 * 512);
    gl_lds16(gb0, Bs[0] + s0 * 512);
    gl_lds16(gb1, Bs[0] + s1 * 512);

    for (int t = 0; t < nt; ++t) {
        __syncthreads();   // buf[t&1] staged (vmcnt drained); prev reads done (lgkm)
        if (t + 1 < nt) {  // stage(t+1) into buf[(t+1)&1] — lands during compute(t)
            const int k0 = (t + 1) << 5;
            const int nb = (t + 1) & 1;
            gl_lds16(ga0 + k0, As[nb] + s0 * 512);
            gl_lds16(ga1 + k0, As[nb] + s1 * 512);
            gl_lds16(gb0 + k0, Bs[nb] + s0 * 512);
            gl_lds16(gb1 + k0, Bs[nb] + s1 * 512);
        }
        const __bf16* as = As[t & 1];
        const __bf16* bs = Bs[t & 1];
        bf16x8 af[4], bfv[4];
#pragma unroll
        for (int i = 0; i < 4; ++i)
            af[i] = *(const bf16x8*)&as[(wr * 64 + i * 16 + l15) * 32 + quad * 8];
#pragma unroll
        for (int j = 0; j < 4; ++j)
            bfv[j] = *(const bf16x8*)&bs[(wc * 64 + j * 16 + l15) * 32 + quad * 8];
#pragma unroll
        for (int i = 0; i < 4; ++i)
#pragma unroll
            for (int j = 0; j < 4; ++j)
                acc[i][j] = __builtin_amdgcn_mfma_f32_16x16x32_bf16(af[i], bfv[j], acc[i][j], 0, 0, 0);
    }

#pragma unroll
    for (int i = 0; i < 4; ++i) {
        const int rg = row0 + wr * 64 + i * 16 + quad * 4;  // rows rg..rg+3
#pragma unroll
        for (int j = 0; j < 4; ++j) {
            const int cg = col0 + wc * 64 + j * 16 + l15;
            const float bb = bias[cg];
            if (MODE == 0) {
                const int b = rg >> 11, n = rg & 2047;     // 4 consecutive n
                const int h = cg >> 6, hd = cg & 63;
                const int nc = n >> 6, ks = (n >> 5) & 1, qj = (n >> 3) & 3, j0 = n & 7;
                const int jt = hd >> 4, fl = hd & 15;
                __bf16* V3 = (__bf16*)Cout;
                bf16x4 v;
#pragma unroll
                for (int r = 0; r < 4; ++r) v[r] = (__bf16)(acc[i][j][r] + bb);
                *(bf16x4*)&V3[(size_t)(((h * 32 + nc) * 4 + b) * 4096) +
                              (jt * 2 + ks) * 512 + fl * 32 + qj * 8 + j0] = v;
            } else {
                float* Cf = (float*)Cout;
#pragma unroll
                for (int r = 0; r < 4; ++r)
                    Cf[(size_t)(rg + r) * N + cg] = acc[i][j][r] + bb;
            }
        }
    }
}

// ---------------------------------------------------------------------------
// attn v8: v7 pipeline, but 64 l-rows per block (grid 16h x 32 = 512 blocks =
// 2 blocks/CU = 16 waves/CU, 4/SIMD).  v7 had 1 block/CU (8 waves, 2/SIMD,
// occupancy 17.7%) and was exposed-latency-bound: per-chunk 3530 cyc vs ~550
// critical-path work — the barrier convoy had only one co-waiter per SIMD.
// Two independent 8-wave barrier domains per CU cover each other's stalls.
// Per-wave i-loop 4 -> 2 (32 l per wave); Ps = 16KB (2buf x 2lh x 2i x 1024).
// V3/r2 re-reads double but stay L2-resident (~42 B/cyc/CU < 56 ceiling).
// ---------------------------------------------------------------------------
__global__ __launch_bounds__(512, 4) void attn_pv_v8(const __bf16* __restrict__ r1b,
                                                     const __bf16* __restrict__ r2t,
                                                     const __bf16* __restrict__ V3,
                                                     __bf16* __restrict__ yb) {
    __shared__ alignas(16) __bf16 Ps[2 * 2 * 2 * 1024];   // [buf][lh][i][...] 16KB
    const int tid = threadIdx.x;
    const int lane = tid & 63;
    const int w = __builtin_amdgcn_readfirstlane(tid >> 6);
    const int b = w & 3, lh = w >> 2;
    const int l15 = lane & 15, quad = lane >> 4;
    const int id = blockIdx.x;
    const int h = id & 15;             // id%8 == h%8 -> per-XCD head locality
    const int l0 = (id >> 4) << 6;     // 32 l-groups of 64

    // r1 B-frags for this wave's 32 l (fixed)
    bf16x8 bf1[2];
#pragma unroll
    for (int i = 0; i < 2; ++i)
        bf1[i] = *(const bf16x8*)&r1b[(size_t)(h * 2048 + l0 + lh * 32 + i * 16 + l15) * 32 + quad * 8];

    const __bf16* r2p = r2t + (size_t)(h * 2048 + b * 16 + l15) * 32 + quad * 8;
    const __bf16* vp = V3 + (size_t)((h * 32) * 4 + b) * 4096 + l15 * 32 + quad * 8;

    // chunk-0 prefetch
    bf16x8 r2f = *(const bf16x8*)r2p;
    bf16x8 vpf[4][2];
#pragma unroll
    for (int jt = 0; jt < 4; ++jt)
#pragma unroll
        for (int ks = 0; ks < 2; ++ks)
            vpf[jt][ks] = *(const bf16x8*)(vp + (jt * 2 + ks) * 512);

    bf16x8 ones;
#pragma unroll
    for (int e = 0; e < 8; ++e) ones[e] = (__bf16)1.0f;

    f32x4 acc[2][4];
    f32x4 den[2];
#pragma unroll
    for (int i = 0; i < 2; ++i) {
        den[i] = (f32x4){0.f, 0.f, 0.f, 0.f};
#pragma unroll
        for (int j = 0; j < 4; ++j) acc[i][j] = (f32x4){0.f, 0.f, 0.f, 0.f};
    }
    const f32x4 zero4 = {0.f, 0.f, 0.f, 0.f};

    const int kw = b >> 1;                       // which ks this wave produces
    const int jg = (b & 1) * 2 + (quad >> 1);    // j-group within frag
    const int q4 = (quad & 1) * 4;
    const int swz = (l15 >> 1) & 3;              // bank swizzle for Ps slots

    // ---- prologue: QK(0) -> exp -> write Ps[0]; prefetch r2f(1)
    f32x4 s[2];
#pragma unroll
    for (int i = 0; i < 2; ++i)
        s[i] = __builtin_amdgcn_mfma_f32_16x16x32_bf16(r2f, bf1[i], zero4, 0, 0, 0);
    r2f = *(const bf16x8*)(r2p + 2048);
    {
        __bf16* ps = &Ps[lh * 2048];
#pragma unroll
        for (int i = 0; i < 2; ++i) {
            bf16x4 p4;
#pragma unroll
            for (int r = 0; r < 4; ++r) p4[r] = (__bf16)__expf(s[i][r]);
            *(bf16x4*)&ps[i * 1024 + kw * 512 + l15 * 32 + ((jg ^ swz) << 3) + q4] = p4;
        }
    }

    for (int c = 0; c < 32; ++c) {
        asm volatile("s_waitcnt lgkmcnt(0)" ::: "memory");
        __builtin_amdgcn_s_barrier();
        const __bf16* ps_r = &Ps[(c & 1) * 4096 + lh * 2048];
        bf16x8 pa[2][2];
#pragma unroll
        for (int i = 0; i < 2; ++i)
#pragma unroll
            for (int ks = 0; ks < 2; ++ks)
                pa[i][ks] = *(const bf16x8*)&ps_r[i * 1024 + ks * 512 + l15 * 32 + ((quad ^ swz) << 3)];
        // QK(c+1): at c=31 this recomputes chunk 31 into a dead buffer
#pragma unroll
        for (int i = 0; i < 2; ++i)
            s[i] = __builtin_amdgcn_mfma_f32_16x16x32_bf16(r2f, bf1[i], zero4, 0, 0, 0);
        const int i2 = (c < 30) ? (c + 2) : 31;
        r2f = *(const bf16x8*)(r2p + (size_t)i2 * 2048);
        // PV(c) + denominators (consume pa, vpf)
#pragma unroll
        for (int ks = 0; ks < 2; ++ks) {
#pragma unroll
            for (int i = 0; i < 2; ++i) {
#pragma unroll
                for (int jt = 0; jt < 4; ++jt)
                    acc[i][jt] = __builtin_amdgcn_mfma_f32_16x16x32_bf16(pa[i][ks], vpf[jt][ks],
                                                                         acc[i][jt], 0, 0, 0);
                den[i] = __builtin_amdgcn_mfma_f32_16x16x32_bf16(pa[i][ks], ones, den[i], 0, 0, 0);
            }
        }
        // exp(c+1) + write Ps[(c+1)&1] — VALU, overlaps PV MFMA issue
        __bf16* ps_w = &Ps[((c + 1) & 1) * 4096 + lh * 2048];
#pragma unroll
        for (int i = 0; i < 2; ++i) {
            bf16x4 p4;
#pragma unroll
            for (int r = 0; r < 4; ++r) p4[r] = (__bf16)__expf(s[i][r]);
            *(bf16x4*)&ps_w[i * 1024 + kw * 512 + l15 * 32 + ((jg ^ swz) << 3) + q4] = p4;
        }
        // V prefetch for chunk c+1 (stays in flight across next barrier)
        const int cv = (c < 31) ? 1 : 0;
        vp += cv * 16384;
#pragma unroll
        for (int jt = 0; jt < 4; ++jt)
#pragma unroll
            for (int ks = 0; ks < 2; ++ks)
                vpf[jt][ks] = *(const bf16x8*)(vp + (jt * 2 + ks) * 512);
    }

    // epilogue: den[i][r] is the softmax denom for l = l0+lh*32+i*16+quad*4+r
#pragma unroll
    for (int i = 0; i < 2; ++i) {
#pragma unroll
        for (int r = 0; r < 4; ++r) {
            const float iv = 1.0f / den[i][r];
            const int l = l0 + lh * 32 + i * 16 + quad * 4 + r;
            const size_t rowbase = ((size_t)b * LL + l) * 1024 + h * 64;
#pragma unroll
            for (int jt = 0; jt < 4; ++jt)
                yb[rowbase + jt * 16 + l15] = (__bf16)(acc[i][jt][r] * iv);
        }
    }
}

extern "C" void kernel_launch(void* const* d_in, const int* in_sizes, int n_in,
                              void* d_out, int out_size, void* d_ws, size_t ws_size,
                              hipStream_t stream) {
    const float* inputs_kv = (const float*)d_in[1];
    const float* Wv = (const float*)d_in[2];   // (D, H*HD)
    const float* bv = (const float*)d_in[3];   // (H*HD)
    const float* r1 = (const float*)d_in[4];   // (H, L, K)
    const float* r2 = (const float*)d_in[5];   // (H, K, L)
    const float* Wo = (const float*)d_in[6];   // (H*HD, D)
    const float* bo = (const float*)d_in[7];   // (D)
    float* out = (float*)d_out;

    char* ws = (char*)d_ws;
    const size_t MB = 1024 * 1024;
    __bf16* A1  = (__bf16*)(ws);             // 16 MB  bf16(inputs_kv) [8192][1024]
    __bf16* Wvt = (__bf16*)(ws + 16 * MB);   //  2 MB  Wv^T
    __bf16* Wot = (__bf16*)(ws + 18 * MB);   //  2 MB  Wo^T
    __bf16* r1b = (__bf16*)(ws + 20 * MB);   //  2 MB  bf16(r1) [h][l][32]
    __bf16* r2t = (__bf16*)(ws + 22 * MB);   //  2 MB  r2^T per head [h][n][32]
    __bf16* V3  = (__bf16*)(ws + 24 * MB);   // 16 MB  V fragment-major (see gemm MODE 0)
    __bf16* yb  = (__bf16*)(ws + 40 * MB);   // 16 MB  y [b][l][h*64+hd]

    prep<<<6144, 256, 0, stream>>>(inputs_kv, r1, Wv, Wo, r2, A1, r1b, Wvt, Wot, r2t);
    gemm_bt<0><<<dim3(8, 64), 256, 0, stream>>>(A1, Wvt, bv, V3, 8192, 1024, 1024);
    attn_pv_v8<<<512, 512, 0, stream>>>(r1b, r2t, V3, yb);
    gemm_bt<1><<<dim3(8, 64), 256, 0, stream>>>(yb, Wot, bo, out, 8192, 1024, 1024);
}

// Round 5
// 236.710 us; speedup vs baseline: 1.0041x; 1.0041x over previous
//
#include <hip/hip_runtime.h>
#include <hip/hip_bf16.h>

// B=4, L=2048, D=1024, H=16, HD=64, K=32, MAXLEN=2048
#define LL 2048

typedef __bf16 bf16x8 __attribute__((ext_vector_type(8)));
typedef __bf16 bf16x4 __attribute__((ext_vector_type(4)));
typedef float f32x4 __attribute__((ext_vector_type(4)));

// async global->LDS, 16B per lane; LDS dest = wave-uniform base + lane*16
__device__ inline void gl_lds16(const __bf16* g, __bf16* l) {
    __builtin_amdgcn_global_load_lds((const __attribute__((address_space(1))) void*)g,
                                     (__attribute__((address_space(3))) void*)l, 16, 0, 0);
}

// ---------------------------------------------------------------------------
// Unified prep: blocks [0,4096) cast inputs_kv->A1; [4096,4608) cast r1->r1b;
// [4608,5120) transpose Wv; [5120,5632) transpose Wo; [5632,6144) transpose r2.
// ---------------------------------------------------------------------------
__global__ __launch_bounds__(256) void prep(const float* __restrict__ inputs_kv,
                                            const float* __restrict__ r1,
                                            const float* __restrict__ Wv,
                                            const float* __restrict__ Wo,
                                            const float* __restrict__ r2,
                                            __bf16* __restrict__ A1,
                                            __bf16* __restrict__ r1b,
                                            __bf16* __restrict__ Wvt,
                                            __bf16* __restrict__ Wot,
                                            __bf16* __restrict__ r2t) {
    __shared__ float Ls[32][65];
    int bid = blockIdx.x;
    const int tid = threadIdx.x;
    if (bid < 4608) {
        const float* in = (bid < 4096) ? inputs_kv : r1;
        __bf16* out = (bid < 4096) ? A1 : r1b;
        const int t = ((bid < 4096) ? bid : bid - 4096) * 256 + tid;
        const float4* in4 = (const float4*)in;
        float4 f0 = in4[t * 2], f1 = in4[t * 2 + 1];
        bf16x8 o;
        o[0] = (__bf16)f0.x; o[1] = (__bf16)f0.y; o[2] = (__bf16)f0.z; o[3] = (__bf16)f0.w;
        o[4] = (__bf16)f1.x; o[5] = (__bf16)f1.y; o[6] = (__bf16)f1.z; o[7] = (__bf16)f1.w;
        *(bf16x8*)&out[(size_t)t * 8] = o;
        return;
    }
    bid -= 4608;
    const float* in;
    __bf16* out;
    int R, C, r0, c0;
    if (bid < 512) {
        in = Wv; out = Wvt; R = 1024; C = 1024;
        c0 = (bid & 15) * 64; r0 = (bid >> 4) * 32;
    } else if (bid < 1024) {
        bid -= 512;
        in = Wo; out = Wot; R = 1024; C = 1024;
        c0 = (bid & 15) * 64; r0 = (bid >> 4) * 32;
    } else {
        bid -= 1024;
        const int bz = bid >> 5;
        in = r2 + (size_t)bz * 65536; out = r2t + (size_t)bz * 65536;
        R = 32; C = 2048;
        c0 = (bid & 31) * 64; r0 = 0;
    }
#pragma unroll
    for (int p = 0; p < 2; ++p) {
        int f = tid + 256 * p;
        int row = f >> 4, c4 = (f & 15) << 2;
        float4 v = *(const float4*)&in[(size_t)(r0 + row) * C + c0 + c4];
        Ls[row][c4 + 0] = v.x; Ls[row][c4 + 1] = v.y;
        Ls[row][c4 + 2] = v.z; Ls[row][c4 + 3] = v.w;
    }
    __syncthreads();
    const int orow = tid >> 2, rc = (tid & 3) << 3;
    bf16x8 o;
#pragma unroll
    for (int j = 0; j < 8; ++j) o[j] = (__bf16)Ls[rc + j][orow];
    *(bf16x8*)&out[(size_t)(c0 + orow) * R + r0 + rc] = o;
}

// ---------------------------------------------------------------------------
// bf16 MFMA GEMM, T3-minimal 2-phase: double-buffered LDS, stage(t+1) issued
// BEFORE compute(t), ONE __syncthreads per K-step.
// XCD-chunked tile swizzle (T1): per-XCD working set 2MB A-slice + 2MB B.
// MODE 0: scatter bf16 V into FRAGMENT-MAJOR layout V3 (see attn).
// MODE 1: write fp32 C[row][col]
// ---------------------------------------------------------------------------
template <int MODE>
__global__ __launch_bounds__(256) void gemm_bt(const __bf16* __restrict__ A,
                                               const __bf16* __restrict__ Bt,
                                               const float* __restrict__ bias,
                                               void* __restrict__ Cout,
                                               int M, int N, int K) {
    __shared__ alignas(16) __bf16 As[2][128 * 32];
    __shared__ alignas(16) __bf16 Bs[2][128 * 32];
    const int tid = threadIdx.x;
    const int lane = tid & 63;
    const int wid = __builtin_amdgcn_readfirstlane(tid >> 6);
    // XCD-chunked swizzle: grid is (8,64) -> 512 flat ids
    const int f = blockIdx.y * 8 + blockIdx.x;
    const int g = (f & 7) * 64 + (f >> 3);
    const int row0 = (g >> 3) * 128, col0 = (g & 7) * 128;
    const int l15 = lane & 15, quad = lane >> 4;
    const int wr = wid & 1, wc = wid >> 1;
    const int s0 = wid * 2, s1 = s0 + 1;

    const __bf16* ga0 = A + (size_t)(row0 + s0 * 16 + (lane >> 2)) * K + ((lane & 3) << 3);
    const __bf16* ga1 = ga0 + (size_t)16 * K;
    const __bf16* gb0 = Bt + (size_t)(col0 + s0 * 16 + (lane >> 2)) * K + ((lane & 3) << 3);
    const __bf16* gb1 = gb0 + (size_t)16 * K;

    f32x4 acc[4][4];
#pragma unroll
    for (int i = 0; i < 4; ++i)
#pragma unroll
        for (int j = 0; j < 4; ++j) acc[i][j] = (f32x4){0.f, 0.f, 0.f, 0.f};

    const int nt = K >> 5;  // K-steps of 32
    // prologue: stage tile 0 into buf 0
    gl_lds16(ga0, As[0] + s0 * 512);
    gl_lds16(ga1, As[0] + s1 * 512);
    gl_lds16(gb0, Bs[0] + s0 * 512);
    gl_lds16(gb1, Bs[0] + s1 * 512);

    for (int t = 0; t < nt; ++t) {
        __syncthreads();   // buf[t&1] staged (vmcnt drained); prev reads done (lgkm)
        if (t + 1 < nt) {  // stage(t+1) into buf[(t+1)&1] — lands during compute(t)
            const int k0 = (t + 1) << 5;
            const int nb = (t + 1) & 1;
            gl_lds16(ga0 + k0, As[nb] + s0 * 512);
            gl_lds16(ga1 + k0, As[nb] + s1 * 512);
            gl_lds16(gb0 + k0, Bs[nb] + s0 * 512);
            gl_lds16(gb1 + k0, Bs[nb] + s1 * 512);
        }
        const __bf16* as = As[t & 1];
        const __bf16* bs = Bs[t & 1];
        bf16x8 af[4], bfv[4];
#pragma unroll
        for (int i = 0; i < 4; ++i)
            af[i] = *(const bf16x8*)&as[(wr * 64 + i * 16 + l15) * 32 + quad * 8];
#pragma unroll
        for (int j = 0; j < 4; ++j)
            bfv[j] = *(const bf16x8*)&bs[(wc * 64 + j * 16 + l15) * 32 + quad * 8];
#pragma unroll
        for (int i = 0; i < 4; ++i)
#pragma unroll
            for (int j = 0; j < 4; ++j)
                acc[i][j] = __builtin_amdgcn_mfma_f32_16x16x32_bf16(af[i], bfv[j], acc[i][j], 0, 0, 0);
    }

#pragma unroll
    for (int i = 0; i < 4; ++i) {
        const int rg = row0 + wr * 64 + i * 16 + quad * 4;  // rows rg..rg+3
#pragma unroll
        for (int j = 0; j < 4; ++j) {
            const int cg = col0 + wc * 64 + j * 16 + l15;
            const float bb = bias[cg];
            if (MODE == 0) {
                const int b = rg >> 11, n = rg & 2047;     // 4 consecutive n
                const int h = cg >> 6, hd = cg & 63;
                const int nc = n >> 6, ks = (n >> 5) & 1, qj = (n >> 3) & 3, j0 = n & 7;
                const int jt = hd >> 4, fl = hd & 15;
                __bf16* V3 = (__bf16*)Cout;
                bf16x4 v;
#pragma unroll
                for (int r = 0; r < 4; ++r) v[r] = (__bf16)(acc[i][j][r] + bb);
                *(bf16x4*)&V3[(size_t)(((h * 32 + nc) * 4 + b) * 4096) +
                              (jt * 2 + ks) * 512 + fl * 32 + qj * 8 + j0] = v;
            } else {
                float* Cf = (float*)Cout;
#pragma unroll
                for (int r = 0; r < 4; ++r)
                    Cf[(size_t)(rg + r) * N + cg] = acc[i][j][r] + bb;
            }
        }
    }
}

// ---------------------------------------------------------------------------
// attn v9: v8 structure (64 l-rows/block, grid 512 = 2 blocks/CU = 16
// waves/CU) but __launch_bounds__(512, 2): VGPR cap 128 instead of v8's
// (512,4) cap of 64.  v8's regression (47->76us) was the 64-VGPR cap: live
// state ~120 regs -> scratch spills in the inner loop (VGPR_Count=64 smoking
// gun; MfmaUtil 37->23 despite occupancy doubling to 34%).  v9 keeps the
// doubled occupancy (LDS 16KB, VGPR <=128 -> 2 blocks/CU) without spills,
// isolating the two-barrier-domain theory.
// ---------------------------------------------------------------------------
__global__ __launch_bounds__(512, 2) void attn_pv_v9(const __bf16* __restrict__ r1b,
                                                     const __bf16* __restrict__ r2t,
                                                     const __bf16* __restrict__ V3,
                                                     __bf16* __restrict__ yb) {
    __shared__ alignas(16) __bf16 Ps[2 * 2 * 2 * 1024];   // [buf][lh][i][...] 16KB
    const int tid = threadIdx.x;
    const int lane = tid & 63;
    const int w = __builtin_amdgcn_readfirstlane(tid >> 6);
    const int b = w & 3, lh = w >> 2;
    const int l15 = lane & 15, quad = lane >> 4;
    const int id = blockIdx.x;
    const int h = id & 15;             // id%8 == h%8 -> per-XCD head locality
    const int l0 = (id >> 4) << 6;     // 32 l-groups of 64

    // r1 B-frags for this wave's 32 l (fixed)
    bf16x8 bf1[2];
#pragma unroll
    for (int i = 0; i < 2; ++i)
        bf1[i] = *(const bf16x8*)&r1b[(size_t)(h * 2048 + l0 + lh * 32 + i * 16 + l15) * 32 + quad * 8];

    const __bf16* r2p = r2t + (size_t)(h * 2048 + b * 16 + l15) * 32 + quad * 8;
    const __bf16* vp = V3 + (size_t)((h * 32) * 4 + b) * 4096 + l15 * 32 + quad * 8;

    // chunk-0 prefetch
    bf16x8 r2f = *(const bf16x8*)r2p;
    bf16x8 vpf[4][2];
#pragma unroll
    for (int jt = 0; jt < 4; ++jt)
#pragma unroll
        for (int ks = 0; ks < 2; ++ks)
            vpf[jt][ks] = *(const bf16x8*)(vp + (jt * 2 + ks) * 512);

    bf16x8 ones;
#pragma unroll
    for (int e = 0; e < 8; ++e) ones[e] = (__bf16)1.0f;

    f32x4 acc[2][4];
    f32x4 den[2];
#pragma unroll
    for (int i = 0; i < 2; ++i) {
        den[i] = (f32x4){0.f, 0.f, 0.f, 0.f};
#pragma unroll
        for (int j = 0; j < 4; ++j) acc[i][j] = (f32x4){0.f, 0.f, 0.f, 0.f};
    }
    const f32x4 zero4 = {0.f, 0.f, 0.f, 0.f};

    const int kw = b >> 1;                       // which ks this wave produces
    const int jg = (b & 1) * 2 + (quad >> 1);    // j-group within frag
    const int q4 = (quad & 1) * 4;
    const int swz = (l15 >> 1) & 3;              // bank swizzle for Ps slots

    // ---- prologue: QK(0) -> exp -> write Ps[0]; prefetch r2f(1)
    f32x4 s[2];
#pragma unroll
    for (int i = 0; i < 2; ++i)
        s[i] = __builtin_amdgcn_mfma_f32_16x16x32_bf16(r2f, bf1[i], zero4, 0, 0, 0);
    r2f = *(const bf16x8*)(r2p + 2048);
    {
        __bf16* ps = &Ps[lh * 2048];
#pragma unroll
        for (int i = 0; i < 2; ++i) {
            bf16x4 p4;
#pragma unroll
            for (int r = 0; r < 4; ++r) p4[r] = (__bf16)__expf(s[i][r]);
            *(bf16x4*)&ps[i * 1024 + kw * 512 + l15 * 32 + ((jg ^ swz) << 3) + q4] = p4;
        }
    }

    for (int c = 0; c < 32; ++c) {
        asm volatile("s_waitcnt lgkmcnt(0)" ::: "memory");
        __builtin_amdgcn_s_barrier();
        const __bf16* ps_r = &Ps[(c & 1) * 4096 + lh * 2048];
        bf16x8 pa[2][2];
#pragma unroll
        for (int i = 0; i < 2; ++i)
#pragma unroll
            for (int ks = 0; ks < 2; ++ks)
                pa[i][ks] = *(const bf16x8*)&ps_r[i * 1024 + ks * 512 + l15 * 32 + ((quad ^ swz) << 3)];
        // QK(c+1): at c=31 this recomputes chunk 31 into a dead buffer
#pragma unroll
        for (int i = 0; i < 2; ++i)
            s[i] = __builtin_amdgcn_mfma_f32_16x16x32_bf16(r2f, bf1[i], zero4, 0, 0, 0);
        const int i2 = (c < 30) ? (c + 2) : 31;
        r2f = *(const bf16x8*)(r2p + (size_t)i2 * 2048);
        // PV(c) + denominators (consume pa, vpf)
#pragma unroll
        for (int ks = 0; ks < 2; ++ks) {
#pragma unroll
            for (int i = 0; i < 2; ++i) {
#pragma unroll
                for (int jt = 0; jt < 4; ++jt)
                    acc[i][jt] = __builtin_amdgcn_mfma_f32_16x16x32_bf16(pa[i][ks], vpf[jt][ks],
                                                                         acc[i][jt], 0, 0, 0);
                den[i] = __builtin_amdgcn_mfma_f32_16x16x32_bf16(pa[i][ks], ones, den[i], 0, 0, 0);
            }
        }
        // exp(c+1) + write Ps[(c+1)&1] — VALU, overlaps PV MFMA issue
        __bf16* ps_w = &Ps[((c + 1) & 1) * 4096 + lh * 2048];
#pragma unroll
        for (int i = 0; i < 2; ++i) {
            bf16x4 p4;
#pragma unroll
            for (int r = 0; r < 4; ++r) p4[r] = (__bf16)__expf(s[i][r]);
            *(bf16x4*)&ps_w[i * 1024 + kw * 512 + l15 * 32 + ((jg ^ swz) << 3) + q4] = p4;
        }
        // V prefetch for chunk c+1 (stays in flight across next barrier)
        const int cv = (c < 31) ? 1 : 0;
        vp += cv * 16384;
#pragma unroll
        for (int jt = 0; jt < 4; ++jt)
#pragma unroll
            for (int ks = 0; ks < 2; ++ks)
                vpf[jt][ks] = *(const bf16x8*)(vp + (jt * 2 + ks) * 512);
    }

    // epilogue: den[i][r] is the softmax denom for l = l0+lh*32+i*16+quad*4+r
#pragma unroll
    for (int i = 0; i < 2; ++i) {
#pragma unroll
        for (int r = 0; r < 4; ++r) {
            const float iv = 1.0f / den[i][r];
            const int l = l0 + lh * 32 + i * 16 + quad * 4 + r;
            const size_t rowbase = ((size_t)b * LL + l) * 1024 + h * 64;
#pragma unroll
            for (int jt = 0; jt < 4; ++jt)
                yb[rowbase + jt * 16 + l15] = (__bf16)(acc[i][jt][r] * iv);
        }
    }
}

extern "C" void kernel_launch(void* const* d_in, const int* in_sizes, int n_in,
                              void* d_out, int out_size, void* d_ws, size_t ws_size,
                              hipStream_t stream) {
    const float* inputs_kv = (const float*)d_in[1];
    const float* Wv = (const float*)d_in[2];   // (D, H*HD)
    const float* bv = (const float*)d_in[3];   // (H*HD)
    const float* r1 = (const float*)d_in[4];   // (H, L, K)
    const float* r2 = (const float*)d_in[5];   // (H, K, L)
    const float* Wo = (const float*)d_in[6];   // (H*HD, D)
    const float* bo = (const float*)d_in[7];   // (D)
    float* out = (float*)d_out;

    char* ws = (char*)d_ws;
    const size_t MB = 1024 * 1024;
    __bf16* A1  = (__bf16*)(ws);             // 16 MB  bf16(inputs_kv) [8192][1024]
    __bf16* Wvt = (__bf16*)(ws + 16 * MB);   //  2 MB  Wv^T
    __bf16* Wot = (__bf16*)(ws + 18 * MB);   //  2 MB  Wo^T
    __bf16* r1b = (__bf16*)(ws + 20 * MB);   //  2 MB  bf16(r1) [h][l][32]
    __bf16* r2t = (__bf16*)(ws + 22 * MB);   //  2 MB  r2^T per head [h][n][32]
    __bf16* V3  = (__bf16*)(ws + 24 * MB);   // 16 MB  V fragment-major (see gemm MODE 0)
    __bf16* yb  = (__bf16*)(ws + 40 * MB);   // 16 MB  y [b][l][h*64+hd]

    prep<<<6144, 256, 0, stream>>>(inputs_kv, r1, Wv, Wo, r2, A1, r1b, Wvt, Wot, r2t);
    gemm_bt<0><<<dim3(8, 64), 256, 0, stream>>>(A1, Wvt, bv, V3, 8192, 1024, 1024);
    attn_pv_v9<<<512, 512, 0, stream>>>(r1b, r2t, V3, yb);
    gemm_bt<1><<<dim3(8, 64), 256, 0, stream>>>(yb, Wot, bo, out, 8192, 1024, 1024);
}

// Round 6
// 233.817 us; speedup vs baseline: 1.0165x; 1.0124x over previous
//
#include <hip/hip_runtime.h>
#include <hip/hip_bf16.h>

// B=4, L=2048, D=1024, H=16, HD=64, K=32, MAXLEN=2048
#define LL 2048

typedef __bf16 bf16x8 __attribute__((ext_vector_type(8)));
typedef __bf16 bf16x4 __attribute__((ext_vector_type(4)));
typedef float f32x4 __attribute__((ext_vector_type(4)));

// async global->LDS, 16B per lane; LDS dest = wave-uniform base + lane*16
__device__ inline void gl_lds16(const __bf16* g, __bf16* l) {
    __builtin_amdgcn_global_load_lds((const __attribute__((address_space(1))) void*)g,
                                     (__attribute__((address_space(3))) void*)l, 16, 0, 0);
}

// ---------------------------------------------------------------------------
// Unified prep: blocks [0,4096) cast inputs_kv->A1; [4096,4608) cast r1->r1b;
// [4608,5120) transpose Wv; [5120,5632) transpose Wo; [5632,6144) transpose r2.
// ---------------------------------------------------------------------------
__global__ __launch_bounds__(256) void prep(const float* __restrict__ inputs_kv,
                                            const float* __restrict__ r1,
                                            const float* __restrict__ Wv,
                                            const float* __restrict__ Wo,
                                            const float* __restrict__ r2,
                                            __bf16* __restrict__ A1,
                                            __bf16* __restrict__ r1b,
                                            __bf16* __restrict__ Wvt,
                                            __bf16* __restrict__ Wot,
                                            __bf16* __restrict__ r2t) {
    __shared__ float Ls[32][65];
    int bid = blockIdx.x;
    const int tid = threadIdx.x;
    if (bid < 4608) {
        const float* in = (bid < 4096) ? inputs_kv : r1;
        __bf16* out = (bid < 4096) ? A1 : r1b;
        const int t = ((bid < 4096) ? bid : bid - 4096) * 256 + tid;
        const float4* in4 = (const float4*)in;
        float4 f0 = in4[t * 2], f1 = in4[t * 2 + 1];
        bf16x8 o;
        o[0] = (__bf16)f0.x; o[1] = (__bf16)f0.y; o[2] = (__bf16)f0.z; o[3] = (__bf16)f0.w;
        o[4] = (__bf16)f1.x; o[5] = (__bf16)f1.y; o[6] = (__bf16)f1.z; o[7] = (__bf16)f1.w;
        *(bf16x8*)&out[(size_t)t * 8] = o;
        return;
    }
    bid -= 4608;
    const float* in;
    __bf16* out;
    int R, C, r0, c0;
    if (bid < 512) {
        in = Wv; out = Wvt; R = 1024; C = 1024;
        c0 = (bid & 15) * 64; r0 = (bid >> 4) * 32;
    } else if (bid < 1024) {
        bid -= 512;
        in = Wo; out = Wot; R = 1024; C = 1024;
        c0 = (bid & 15) * 64; r0 = (bid >> 4) * 32;
    } else {
        bid -= 1024;
        const int bz = bid >> 5;
        in = r2 + (size_t)bz * 65536; out = r2t + (size_t)bz * 65536;
        R = 32; C = 2048;
        c0 = (bid & 31) * 64; r0 = 0;
    }
#pragma unroll
    for (int p = 0; p < 2; ++p) {
        int f = tid + 256 * p;
        int row = f >> 4, c4 = (f & 15) << 2;
        float4 v = *(const float4*)&in[(size_t)(r0 + row) * C + c0 + c4];
        Ls[row][c4 + 0] = v.x; Ls[row][c4 + 1] = v.y;
        Ls[row][c4 + 2] = v.z; Ls[row][c4 + 3] = v.w;
    }
    __syncthreads();
    const int orow = tid >> 2, rc = (tid & 3) << 3;
    bf16x8 o;
#pragma unroll
    for (int j = 0; j < 8; ++j) o[j] = (__bf16)Ls[rc + j][orow];
    *(bf16x8*)&out[(size_t)(c0 + orow) * R + r0 + rc] = o;
}

// ---------------------------------------------------------------------------
// bf16 MFMA GEMM, hybrid operand path. Per-CU per-K-step the old all-LDS
// version moved 64KB through the LDS pipe (64 x ds_read_b128 ~ 770cyc at
// 85B/cyc) vs ~155cyc of MFMA -> LDS-read-throughput bound (this is also why
// R4's dbuf was a null result). Fix: B (Wvt/Wot, 2MB, L2-resident per XCD
// thanks to the T1 swizzle) is loaded DIRECTLY global->reg per fragment
// (16 rows x 64B contiguous, same pattern attn uses for V3), prefetched one
// K-step ahead. LDS holds only A: reads halve to ~385cyc and B bytes move to
// the independent L1 pipe. A stays double-buffered via global_load_lds.
// MODE 0: scatter bf16 V into FRAGMENT-MAJOR layout V3 (see attn).
// MODE 1: write fp32 C[row][col]
// ---------------------------------------------------------------------------
template <int MODE>
__global__ __launch_bounds__(256) void gemm_bt(const __bf16* __restrict__ A,
                                               const __bf16* __restrict__ Bt,
                                               const float* __restrict__ bias,
                                               void* __restrict__ Cout,
                                               int M, int N, int K) {
    __shared__ alignas(16) __bf16 As[2][128 * 32];
    const int tid = threadIdx.x;
    const int lane = tid & 63;
    const int wid = __builtin_amdgcn_readfirstlane(tid >> 6);
    // XCD-chunked swizzle: grid is (8,64) -> 512 flat ids
    const int f = blockIdx.y * 8 + blockIdx.x;
    const int g = (f & 7) * 64 + (f >> 3);
    const int row0 = (g >> 3) * 128, col0 = (g & 7) * 128;
    const int l15 = lane & 15, quad = lane >> 4;
    const int wr = wid & 1, wc = wid >> 1;
    const int s0 = wid * 2, s1 = s0 + 1;

    const __bf16* ga0 = A + (size_t)(row0 + s0 * 16 + (lane >> 2)) * K + ((lane & 3) << 3);
    const __bf16* ga1 = ga0 + (size_t)16 * K;
    // B fragment base: frag j rows = col0 + wc*64 + j*16 + l15, k-offset quad*8
    const __bf16* gB = Bt + (size_t)(col0 + wc * 64 + l15) * K + quad * 8;

    f32x4 acc[4][4];
#pragma unroll
    for (int i = 0; i < 4; ++i)
#pragma unroll
        for (int j = 0; j < 4; ++j) acc[i][j] = (f32x4){0.f, 0.f, 0.f, 0.f};

    const int nt = K >> 5;  // K-steps of 32
    // prologue: stage A-tile 0 into buf 0; load B-frags for t=0
    gl_lds16(ga0, As[0] + s0 * 512);
    gl_lds16(ga1, As[0] + s1 * 512);
    bf16x8 bcur[4], bnxt[4];
#pragma unroll
    for (int j = 0; j < 4; ++j)
        bcur[j] = *(const bf16x8*)(gB + (size_t)j * 16 * K);

    for (int t = 0; t < nt; ++t) {
        __syncthreads();   // As[t&1] staged (vmcnt drained); prev reads done
        if (t + 1 < nt) {  // issue next A-stage + B-frag loads; land during MFMA(t)
            const int k0 = (t + 1) << 5;
            const int nb = (t + 1) & 1;
            gl_lds16(ga0 + k0, As[nb] + s0 * 512);
            gl_lds16(ga1 + k0, As[nb] + s1 * 512);
#pragma unroll
            for (int j = 0; j < 4; ++j)
                bnxt[j] = *(const bf16x8*)(gB + (size_t)j * 16 * K + k0);
        }
        const __bf16* as = As[t & 1];
        bf16x8 af[4];
#pragma unroll
        for (int i = 0; i < 4; ++i)
            af[i] = *(const bf16x8*)&as[(wr * 64 + i * 16 + l15) * 32 + quad * 8];
#pragma unroll
        for (int i = 0; i < 4; ++i)
#pragma unroll
            for (int j = 0; j < 4; ++j)
                acc[i][j] = __builtin_amdgcn_mfma_f32_16x16x32_bf16(af[i], bcur[j], acc[i][j], 0, 0, 0);
        if (t + 1 < nt) {
#pragma unroll
            for (int j = 0; j < 4; ++j) bcur[j] = bnxt[j];
        }
    }

#pragma unroll
    for (int i = 0; i < 4; ++i) {
        const int rg = row0 + wr * 64 + i * 16 + quad * 4;  // rows rg..rg+3
#pragma unroll
        for (int j = 0; j < 4; ++j) {
            const int cg = col0 + wc * 64 + j * 16 + l15;
            const float bb = bias[cg];
            if (MODE == 0) {
                const int b = rg >> 11, n = rg & 2047;     // 4 consecutive n
                const int h = cg >> 6, hd = cg & 63;
                const int nc = n >> 6, ks = (n >> 5) & 1, qj = (n >> 3) & 3, j0 = n & 7;
                const int jt = hd >> 4, fl = hd & 15;
                __bf16* V3 = (__bf16*)Cout;
                bf16x4 v;
#pragma unroll
                for (int r = 0; r < 4; ++r) v[r] = (__bf16)(acc[i][j][r] + bb);
                *(bf16x4*)&V3[(size_t)(((h * 32 + nc) * 4 + b) * 4096) +
                              (jt * 2 + ks) * 512 + fl * 32 + qj * 8 + j0] = v;
            } else {
                float* Cf = (float*)Cout;
#pragma unroll
                for (int r = 0; r < 4; ++r)
                    Cf[(size_t)(rg + r) * N + cg] = acc[i][j][r] + bb;
            }
        }
    }
}

// ---------------------------------------------------------------------------
// attn v7 (reverted from v8/v9): proven 47.1us. 512 thr, 8 waves, 1 block/CU,
// XOR-swizzled Ps, chunk-level software pipeline:
//   lgkmcnt(0); s_barrier (raw: vmcnt NOT drained -> prefetches in flight)
//   pa <- Ps[c&1]; QK(c+1); PV(c); exp(c+1)->Ps[(c+1)&1]; prefetch V,r2.
// v8/v9 post-mortem: the 2-blocks/CU variants pinned VGPR to 64 (launch_
// bounds second-arg semantics) -> inner-loop spills -> 76us. The 16-wave
// occupancy experiment is parked; plain (512) gives VGPR 88, no spills.
// ---------------------------------------------------------------------------
__global__ __launch_bounds__(512) void attn_pv_v7(const __bf16* __restrict__ r1b,
                                                  const __bf16* __restrict__ r2t,
                                                  const __bf16* __restrict__ V3,
                                                  __bf16* __restrict__ yb) {
    __shared__ alignas(16) __bf16 Ps[2 * 2 * 4 * 1024];   // [buf][lh][i][ks*512+...] 32KB
    const int tid = threadIdx.x;
    const int lane = tid & 63;
    const int w = __builtin_amdgcn_readfirstlane(tid >> 6);
    const int b = w & 3, lh = w >> 2;
    const int l15 = lane & 15, quad = lane >> 4;
    const int id = blockIdx.x;
    const int h = id & 15;             // id%8 == h%8 -> per-XCD head locality
    const int l0 = (id >> 4) << 7;

    // r1 B-frags for this wave's 64 l (fixed)
    bf16x8 bf1[4];
#pragma unroll
    for (int i = 0; i < 4; ++i)
        bf1[i] = *(const bf16x8*)&r1b[(size_t)(h * 2048 + l0 + lh * 64 + i * 16 + l15) * 32 + quad * 8];

    const __bf16* r2p = r2t + (size_t)(h * 2048 + b * 16 + l15) * 32 + quad * 8;
    const __bf16* vp = V3 + (size_t)((h * 32) * 4 + b) * 4096 + l15 * 32 + quad * 8;

    // chunk-0 prefetch
    bf16x8 r2f = *(const bf16x8*)r2p;
    bf16x8 vpf[4][2];
#pragma unroll
    for (int jt = 0; jt < 4; ++jt)
#pragma unroll
        for (int ks = 0; ks < 2; ++ks)
            vpf[jt][ks] = *(const bf16x8*)(vp + (jt * 2 + ks) * 512);

    bf16x8 ones;
#pragma unroll
    for (int e = 0; e < 8; ++e) ones[e] = (__bf16)1.0f;

    f32x4 acc[4][4];
    f32x4 den[4];
#pragma unroll
    for (int i = 0; i < 4; ++i) {
        den[i] = (f32x4){0.f, 0.f, 0.f, 0.f};
#pragma unroll
        for (int j = 0; j < 4; ++j) acc[i][j] = (f32x4){0.f, 0.f, 0.f, 0.f};
    }
    const f32x4 zero4 = {0.f, 0.f, 0.f, 0.f};

    const int kw = b >> 1;                       // which ks this wave produces
    const int jg = (b & 1) * 2 + (quad >> 1);    // j-group within frag
    const int q4 = (quad & 1) * 4;
    const int swz = (l15 >> 1) & 3;              // bank swizzle for Ps slots

    // ---- prologue: QK(0) -> exp -> write Ps[0]; prefetch r2f(1)
    f32x4 s[4];
#pragma unroll
    for (int i = 0; i < 4; ++i)
        s[i] = __builtin_amdgcn_mfma_f32_16x16x32_bf16(r2f, bf1[i], zero4, 0, 0, 0);
    r2f = *(const bf16x8*)(r2p + 2048);
    {
        __bf16* ps = &Ps[lh * 4096];
#pragma unroll
        for (int i = 0; i < 4; ++i) {
            bf16x4 p4;
#pragma unroll
            for (int r = 0; r < 4; ++r) p4[r] = (__bf16)__expf(s[i][r]);
            *(bf16x4*)&ps[i * 1024 + kw * 512 + l15 * 32 + ((jg ^ swz) << 3) + q4] = p4;
        }
    }

    for (int c = 0; c < 32; ++c) {
        asm volatile("s_waitcnt lgkmcnt(0)" ::: "memory");
        __builtin_amdgcn_s_barrier();
        const __bf16* ps_r = &Ps[((c & 1) * 2 + lh) * 4096];
        bf16x8 pa[4][2];
#pragma unroll
        for (int i = 0; i < 4; ++i)
#pragma unroll
            for (int ks = 0; ks < 2; ++ks)
                pa[i][ks] = *(const bf16x8*)&ps_r[i * 1024 + ks * 512 + l15 * 32 + ((quad ^ swz) << 3)];
        // QK(c+1): at c=31 this recomputes chunk 31 into a dead buffer
#pragma unroll
        for (int i = 0; i < 4; ++i)
            s[i] = __builtin_amdgcn_mfma_f32_16x16x32_bf16(r2f, bf1[i], zero4, 0, 0, 0);
        const int i2 = (c < 30) ? (c + 2) : 31;
        r2f = *(const bf16x8*)(r2p + (size_t)i2 * 2048);
        // PV(c) + denominators (consume pa, vpf)
#pragma unroll
        for (int ks = 0; ks < 2; ++ks) {
#pragma unroll
            for (int i = 0; i < 4; ++i) {
#pragma unroll
                for (int jt = 0; jt < 4; ++jt)
                    acc[i][jt] = __builtin_amdgcn_mfma_f32_16x16x32_bf16(pa[i][ks], vpf[jt][ks],
                                                                         acc[i][jt], 0, 0, 0);
                den[i] = __builtin_amdgcn_mfma_f32_16x16x32_bf16(pa[i][ks], ones, den[i], 0, 0, 0);
            }
        }
        // exp(c+1) + write Ps[(c+1)&1] — VALU, overlaps PV MFMA issue
        __bf16* ps_w = &Ps[(((c + 1) & 1) * 2 + lh) * 4096];
#pragma unroll
        for (int i = 0; i < 4; ++i) {
            bf16x4 p4;
#pragma unroll
            for (int r = 0; r < 4; ++r) p4[r] = (__bf16)__expf(s[i][r]);
            *(bf16x4*)&ps_w[i * 1024 + kw * 512 + l15 * 32 + ((jg ^ swz) << 3) + q4] = p4;
        }
        // V prefetch for chunk c+1 (stays in flight across next barrier)
        const int cv = (c < 31) ? 1 : 0;
        vp += cv * 16384;
#pragma unroll
        for (int jt = 0; jt < 4; ++jt)
#pragma unroll
            for (int ks = 0; ks < 2; ++ks)
                vpf[jt][ks] = *(const bf16x8*)(vp + (jt * 2 + ks) * 512);
    }

    // epilogue: den[i][r] is the softmax denom for l = lh*64+i*16+quad*4+r (per-lane!)
#pragma unroll
    for (int i = 0; i < 4; ++i) {
#pragma unroll
        for (int r = 0; r < 4; ++r) {
            const float iv = 1.0f / den[i][r];
            const int l = l0 + lh * 64 + i * 16 + quad * 4 + r;
            const size_t rowbase = ((size_t)b * LL + l) * 1024 + h * 64;
#pragma unroll
            for (int jt = 0; jt < 4; ++jt)
                yb[rowbase + jt * 16 + l15] = (__bf16)(acc[i][jt][r] * iv);
        }
    }
}

extern "C" void kernel_launch(void* const* d_in, const int* in_sizes, int n_in,
                              void* d_out, int out_size, void* d_ws, size_t ws_size,
                              hipStream_t stream) {
    const float* inputs_kv = (const float*)d_in[1];
    const float* Wv = (const float*)d_in[2];   // (D, H*HD)
    const float* bv = (const float*)d_in[3];   // (H*HD)
    const float* r1 = (const float*)d_in[4];   // (H, L, K)
    const float* r2 = (const float*)d_in[5];   // (H, K, L)
    const float* Wo = (const float*)d_in[6];   // (H*HD, D)
    const float* bo = (const float*)d_in[7];   // (D)
    float* out = (float*)d_out;

    char* ws = (char*)d_ws;
    const size_t MB = 1024 * 1024;
    __bf16* A1  = (__bf16*)(ws);             // 16 MB  bf16(inputs_kv) [8192][1024]
    __bf16* Wvt = (__bf16*)(ws + 16 * MB);   //  2 MB  Wv^T
    __bf16* Wot = (__bf16*)(ws + 18 * MB);   //  2 MB  Wo^T
    __bf16* r1b = (__bf16*)(ws + 20 * MB);   //  2 MB  bf16(r1) [h][l][32]
    __bf16* r2t = (__bf16*)(ws + 22 * MB);   //  2 MB  r2^T per head [h][n][32]
    __bf16* V3  = (__bf16*)(ws + 24 * MB);   // 16 MB  V fragment-major (see gemm MODE 0)
    __bf16* yb  = (__bf16*)(ws + 40 * MB);   // 16 MB  y [b][l][h*64+hd]

    prep<<<6144, 256, 0, stream>>>(inputs_kv, r1, Wv, Wo, r2, A1, r1b, Wvt, Wot, r2t);
    gemm_bt<0><<<dim3(8, 64), 256, 0, stream>>>(A1, Wvt, bv, V3, 8192, 1024, 1024);
    attn_pv_v7<<<256, 512, 0, stream>>>(r1b, r2t, V3, yb);
    gemm_bt<1><<<dim3(8, 64), 256, 0, stream>>>(yb, Wot, bo, out, 8192, 1024, 1024);
}

// Round 7
// 211.177 us; speedup vs baseline: 1.1255x; 1.1072x over previous
//
#include <hip/hip_runtime.h>
#include <hip/hip_bf16.h>

// B=4, L=2048, D=1024, H=16, HD=64, K=32, MAXLEN=2048
#define LL 2048

typedef __bf16 bf16x8 __attribute__((ext_vector_type(8)));
typedef __bf16 bf16x4 __attribute__((ext_vector_type(4)));
typedef float f32x4 __attribute__((ext_vector_type(4)));

// async global->LDS, 16B per lane; LDS dest = wave-uniform base + lane*16
__device__ inline void gl_lds16(const __bf16* g, __bf16* l) {
    __builtin_amdgcn_global_load_lds((const __attribute__((address_space(1))) void*)g,
                                     (__attribute__((address_space(3))) void*)l, 16, 0, 0);
}

// ---------------------------------------------------------------------------
// Unified prep: blocks [0,4096) cast inputs_kv->A1; [4096,4608) cast r1->r1b;
// [4608,5120) transpose Wv; [5120,5632) transpose Wo; [5632,6144) transpose r2.
// ---------------------------------------------------------------------------
__global__ __launch_bounds__(256) void prep(const float* __restrict__ inputs_kv,
                                            const float* __restrict__ r1,
                                            const float* __restrict__ Wv,
                                            const float* __restrict__ Wo,
                                            const float* __restrict__ r2,
                                            __bf16* __restrict__ A1,
                                            __bf16* __restrict__ r1b,
                                            __bf16* __restrict__ Wvt,
                                            __bf16* __restrict__ Wot,
                                            __bf16* __restrict__ r2t) {
    __shared__ float Ls[32][65];
    int bid = blockIdx.x;
    const int tid = threadIdx.x;
    if (bid < 4608) {
        const float* in = (bid < 4096) ? inputs_kv : r1;
        __bf16* out = (bid < 4096) ? A1 : r1b;
        const int t = ((bid < 4096) ? bid : bid - 4096) * 256 + tid;
        const float4* in4 = (const float4*)in;
        float4 f0 = in4[t * 2], f1 = in4[t * 2 + 1];
        bf16x8 o;
        o[0] = (__bf16)f0.x; o[1] = (__bf16)f0.y; o[2] = (__bf16)f0.z; o[3] = (__bf16)f0.w;
        o[4] = (__bf16)f1.x; o[5] = (__bf16)f1.y; o[6] = (__bf16)f1.z; o[7] = (__bf16)f1.w;
        *(bf16x8*)&out[(size_t)t * 8] = o;
        return;
    }
    bid -= 4608;
    const float* in;
    __bf16* out;
    int R, C, r0, c0;
    if (bid < 512) {
        in = Wv; out = Wvt; R = 1024; C = 1024;
        c0 = (bid & 15) * 64; r0 = (bid >> 4) * 32;
    } else if (bid < 1024) {
        bid -= 512;
        in = Wo; out = Wot; R = 1024; C = 1024;
        c0 = (bid & 15) * 64; r0 = (bid >> 4) * 32;
    } else {
        bid -= 1024;
        const int bz = bid >> 5;
        in = r2 + (size_t)bz * 65536; out = r2t + (size_t)bz * 65536;
        R = 32; C = 2048;
        c0 = (bid & 31) * 64; r0 = 0;
    }
#pragma unroll
    for (int p = 0; p < 2; ++p) {
        int f = tid + 256 * p;
        int row = f >> 4, c4 = (f & 15) << 2;
        float4 v = *(const float4*)&in[(size_t)(r0 + row) * C + c0 + c4];
        Ls[row][c4 + 0] = v.x; Ls[row][c4 + 1] = v.y;
        Ls[row][c4 + 2] = v.z; Ls[row][c4 + 3] = v.w;
    }
    __syncthreads();
    const int orow = tid >> 2, rc = (tid & 3) << 3;
    bf16x8 o;
#pragma unroll
    for (int j = 0; j < 8; ++j) o[j] = (__bf16)Ls[rc + j][orow];
    *(bf16x8*)&out[(size_t)(c0 + orow) * R + r0 + rc] = o;
}

// ---------------------------------------------------------------------------
// bf16 MFMA GEMM, 3-buffer depth-2 pipeline with COUNTED vmcnt (T3+T4).
// R6 post-mortem: B-from-global regressed (+25us) -> B back in LDS.
// R4/R5 dbuf post-mortem: __syncthreads drains vmcnt(0) every K-step; A's
// dirty lines sit in OTHER XCDs' L2s (prep wrote round-robin) -> ~500-900cyc
// remote fetch exposed per step (measured ~3400cyc/step vs ~1070 work).
// Now: stage(t+2) issued at iter t; before consuming buf(t) wait vmcnt(4)
// (leaves stage(t+1)'s 4 loads in flight ACROSS the barrier - never 0 in
// loop). Each wave issues exactly 4 gl_lds16/step so the count is exact.
// WAR on buf[(t+2)%3]: its last reads were iter t-1, retired via MFMA
// consumption before barrier(t); stage(t+2) issues after barrier(t). 1 raw
// barrier/step. LDS 48KB -> still 2 blocks/CU.
// XCD-chunked tile swizzle (T1): per-XCD working set 2MB A-slice + 2MB B.
// MODE 0: scatter bf16 V into FRAGMENT-MAJOR layout V3 (see attn).
// MODE 1: write fp32 C[row][col]
// ---------------------------------------------------------------------------
template <int MODE>
__global__ __launch_bounds__(256) void gemm_bt(const __bf16* __restrict__ A,
                                               const __bf16* __restrict__ Bt,
                                               const float* __restrict__ bias,
                                               void* __restrict__ Cout,
                                               int M, int N, int K) {
    __shared__ alignas(16) __bf16 As[3][128 * 32];
    __shared__ alignas(16) __bf16 Bs[3][128 * 32];
    const int tid = threadIdx.x;
    const int lane = tid & 63;
    const int wid = __builtin_amdgcn_readfirstlane(tid >> 6);
    // XCD-chunked swizzle: grid is (8,64) -> 512 flat ids
    const int f = blockIdx.y * 8 + blockIdx.x;
    const int g = (f & 7) * 64 + (f >> 3);
    const int row0 = (g >> 3) * 128, col0 = (g & 7) * 128;
    const int l15 = lane & 15, quad = lane >> 4;
    const int wr = wid & 1, wc = wid >> 1;
    const int s0 = wid * 2, s1 = s0 + 1;

    const __bf16* ga0 = A + (size_t)(row0 + s0 * 16 + (lane >> 2)) * K + ((lane & 3) << 3);
    const __bf16* ga1 = ga0 + (size_t)16 * K;
    const __bf16* gb0 = Bt + (size_t)(col0 + s0 * 16 + (lane >> 2)) * K + ((lane & 3) << 3);
    const __bf16* gb1 = gb0 + (size_t)16 * K;

    f32x4 acc[4][4];
#pragma unroll
    for (int i = 0; i < 4; ++i)
#pragma unroll
        for (int j = 0; j < 4; ++j) acc[i][j] = (f32x4){0.f, 0.f, 0.f, 0.f};

    const int nt = K >> 5;  // K-steps of 32

    // prologue: stage tiles 0,1 into bufs 0,1 (8 loads/wave outstanding)
    gl_lds16(ga0, As[0] + s0 * 512);
    gl_lds16(ga1, As[0] + s1 * 512);
    gl_lds16(gb0, Bs[0] + s0 * 512);
    gl_lds16(gb1, Bs[0] + s1 * 512);
    if (nt > 1) {
        gl_lds16(ga0 + 32, As[1] + s0 * 512);
        gl_lds16(ga1 + 32, As[1] + s1 * 512);
        gl_lds16(gb0 + 32, Bs[1] + s0 * 512);
        gl_lds16(gb1 + 32, Bs[1] + s1 * 512);
    }

    int cur = 0;
    for (int t = 0; t < nt; ++t) {
        // guarantee stage(t) landed; keep stage(t+1) in flight (counted wait)
        if (t + 1 < nt) {
            asm volatile("s_waitcnt vmcnt(4)" ::: "memory");
        } else {
            asm volatile("s_waitcnt vmcnt(0)" ::: "memory");
        }
        __builtin_amdgcn_s_barrier();
        if (t + 2 < nt) {   // stage(t+2) into buf (cur+2)%3; lands during t,t+1
            int nb = cur + 2; if (nb >= 3) nb -= 3;
            const int k0 = (t + 2) << 5;
            gl_lds16(ga0 + k0, As[nb] + s0 * 512);
            gl_lds16(ga1 + k0, As[nb] + s1 * 512);
            gl_lds16(gb0 + k0, Bs[nb] + s0 * 512);
            gl_lds16(gb1 + k0, Bs[nb] + s1 * 512);
        }
        const __bf16* as = As[cur];
        const __bf16* bs = Bs[cur];
        bf16x8 af[4], bfv[4];
#pragma unroll
        for (int i = 0; i < 4; ++i)
            af[i] = *(const bf16x8*)&as[(wr * 64 + i * 16 + l15) * 32 + quad * 8];
#pragma unroll
        for (int j = 0; j < 4; ++j)
            bfv[j] = *(const bf16x8*)&bs[(wc * 64 + j * 16 + l15) * 32 + quad * 8];
#pragma unroll
        for (int i = 0; i < 4; ++i)
#pragma unroll
            for (int j = 0; j < 4; ++j)
                acc[i][j] = __builtin_amdgcn_mfma_f32_16x16x32_bf16(af[i], bfv[j], acc[i][j], 0, 0, 0);
        cur = (cur + 1 == 3) ? 0 : cur + 1;
    }

#pragma unroll
    for (int i = 0; i < 4; ++i) {
        const int rg = row0 + wr * 64 + i * 16 + quad * 4;  // rows rg..rg+3
#pragma unroll
        for (int j = 0; j < 4; ++j) {
            const int cg = col0 + wc * 64 + j * 16 + l15;
            const float bb = bias[cg];
            if (MODE == 0) {
                const int b = rg >> 11, n = rg & 2047;     // 4 consecutive n
                const int h = cg >> 6, hd = cg & 63;
                const int nc = n >> 6, ks = (n >> 5) & 1, qj = (n >> 3) & 3, j0 = n & 7;
                const int jt = hd >> 4, fl = hd & 15;
                __bf16* V3 = (__bf16*)Cout;
                bf16x4 v;
#pragma unroll
                for (int r = 0; r < 4; ++r) v[r] = (__bf16)(acc[i][j][r] + bb);
                *(bf16x4*)&V3[(size_t)(((h * 32 + nc) * 4 + b) * 4096) +
                              (jt * 2 + ks) * 512 + fl * 32 + qj * 8 + j0] = v;
            } else {
                float* Cf = (float*)Cout;
#pragma unroll
                for (int r = 0; r < 4; ++r)
                    Cf[(size_t)(rg + r) * N + cg] = acc[i][j][r] + bb;
            }
        }
    }
}

// ---------------------------------------------------------------------------
// attn v7 (proven 47-48us): 512 thr, 8 waves, 1 block/CU, XOR-swizzled Ps,
// chunk-level software pipeline:
//   lgkmcnt(0); s_barrier (raw: vmcnt NOT drained -> prefetches in flight)
//   pa <- Ps[c&1]; QK(c+1); PV(c); exp(c+1)->Ps[(c+1)&1]; prefetch V,r2.
// v8/v9 post-mortem: 2-blocks/CU launch-bounds variants pinned VGPR to 64 ->
// inner-loop spills -> 76us. Occupancy experiment parked; plain (512) gives
// VGPR 88, no spills.
// ---------------------------------------------------------------------------
__global__ __launch_bounds__(512) void attn_pv_v7(const __bf16* __restrict__ r1b,
                                                  const __bf16* __restrict__ r2t,
                                                  const __bf16* __restrict__ V3,
                                                  __bf16* __restrict__ yb) {
    __shared__ alignas(16) __bf16 Ps[2 * 2 * 4 * 1024];   // [buf][lh][i][ks*512+...] 32KB
    const int tid = threadIdx.x;
    const int lane = tid & 63;
    const int w = __builtin_amdgcn_readfirstlane(tid >> 6);
    const int b = w & 3, lh = w >> 2;
    const int l15 = lane & 15, quad = lane >> 4;
    const int id = blockIdx.x;
    const int h = id & 15;             // id%8 == h%8 -> per-XCD head locality
    const int l0 = (id >> 4) << 7;

    // r1 B-frags for this wave's 64 l (fixed)
    bf16x8 bf1[4];
#pragma unroll
    for (int i = 0; i < 4; ++i)
        bf1[i] = *(const bf16x8*)&r1b[(size_t)(h * 2048 + l0 + lh * 64 + i * 16 + l15) * 32 + quad * 8];

    const __bf16* r2p = r2t + (size_t)(h * 2048 + b * 16 + l15) * 32 + quad * 8;
    const __bf16* vp = V3 + (size_t)((h * 32) * 4 + b) * 4096 + l15 * 32 + quad * 8;

    // chunk-0 prefetch
    bf16x8 r2f = *(const bf16x8*)r2p;
    bf16x8 vpf[4][2];
#pragma unroll
    for (int jt = 0; jt < 4; ++jt)
#pragma unroll
        for (int ks = 0; ks < 2; ++ks)
            vpf[jt][ks] = *(const bf16x8*)(vp + (jt * 2 + ks) * 512);

    bf16x8 ones;
#pragma unroll
    for (int e = 0; e < 8; ++e) ones[e] = (__bf16)1.0f;

    f32x4 acc[4][4];
    f32x4 den[4];
#pragma unroll
    for (int i = 0; i < 4; ++i) {
        den[i] = (f32x4){0.f, 0.f, 0.f, 0.f};
#pragma unroll
        for (int j = 0; j < 4; ++j) acc[i][j] = (f32x4){0.f, 0.f, 0.f, 0.f};
    }
    const f32x4 zero4 = {0.f, 0.f, 0.f, 0.f};

    const int kw = b >> 1;                       // which ks this wave produces
    const int jg = (b & 1) * 2 + (quad >> 1);    // j-group within frag
    const int q4 = (quad & 1) * 4;
    const int swz = (l15 >> 1) & 3;              // bank swizzle for Ps slots

    // ---- prologue: QK(0) -> exp -> write Ps[0]; prefetch r2f(1)
    f32x4 s[4];
#pragma unroll
    for (int i = 0; i < 4; ++i)
        s[i] = __builtin_amdgcn_mfma_f32_16x16x32_bf16(r2f, bf1[i], zero4, 0, 0, 0);
    r2f = *(const bf16x8*)(r2p + 2048);
    {
        __bf16* ps = &Ps[lh * 4096];
#pragma unroll
        for (int i = 0; i < 4; ++i) {
            bf16x4 p4;
#pragma unroll
            for (int r = 0; r < 4; ++r) p4[r] = (__bf16)__expf(s[i][r]);
            *(bf16x4*)&ps[i * 1024 + kw * 512 + l15 * 32 + ((jg ^ swz) << 3) + q4] = p4;
        }
    }

    for (int c = 0; c < 32; ++c) {
        asm volatile("s_waitcnt lgkmcnt(0)" ::: "memory");
        __builtin_amdgcn_s_barrier();
        const __bf16* ps_r = &Ps[((c & 1) * 2 + lh) * 4096];
        bf16x8 pa[4][2];
#pragma unroll
        for (int i = 0; i < 4; ++i)
#pragma unroll
            for (int ks = 0; ks < 2; ++ks)
                pa[i][ks] = *(const bf16x8*)&ps_r[i * 1024 + ks * 512 + l15 * 32 + ((quad ^ swz) << 3)];
        // QK(c+1): at c=31 this recomputes chunk 31 into a dead buffer
#pragma unroll
        for (int i = 0; i < 4; ++i)
            s[i] = __builtin_amdgcn_mfma_f32_16x16x32_bf16(r2f, bf1[i], zero4, 0, 0, 0);
        const int i2 = (c < 30) ? (c + 2) : 31;
        r2f = *(const bf16x8*)(r2p + (size_t)i2 * 2048);
        // PV(c) + denominators (consume pa, vpf)
#pragma unroll
        for (int ks = 0; ks < 2; ++ks) {
#pragma unroll
            for (int i = 0; i < 4; ++i) {
#pragma unroll
                for (int jt = 0; jt < 4; ++jt)
                    acc[i][jt] = __builtin_amdgcn_mfma_f32_16x16x32_bf16(pa[i][ks], vpf[jt][ks],
                                                                         acc[i][jt], 0, 0, 0);
                den[i] = __builtin_amdgcn_mfma_f32_16x16x32_bf16(pa[i][ks], ones, den[i], 0, 0, 0);
            }
        }
        // exp(c+1) + write Ps[(c+1)&1] — VALU, overlaps PV MFMA issue
        __bf16* ps_w = &Ps[(((c + 1) & 1) * 2 + lh) * 4096];
#pragma unroll
        for (int i = 0; i < 4; ++i) {
            bf16x4 p4;
#pragma unroll
            for (int r = 0; r < 4; ++r) p4[r] = (__bf16)__expf(s[i][r]);
            *(bf16x4*)&ps_w[i * 1024 + kw * 512 + l15 * 32 + ((jg ^ swz) << 3) + q4] = p4;
        }
        // V prefetch for chunk c+1 (stays in flight across next barrier)
        const int cv = (c < 31) ? 1 : 0;
        vp += cv * 16384;
#pragma unroll
        for (int jt = 0; jt < 4; ++jt)
#pragma unroll
            for (int ks = 0; ks < 2; ++ks)
                vpf[jt][ks] = *(const bf16x8*)(vp + (jt * 2 + ks) * 512);
    }

    // epilogue: den[i][r] is the softmax denom for l = lh*64+i*16+quad*4+r (per-lane!)
#pragma unroll
    for (int i = 0; i < 4; ++i) {
#pragma unroll
        for (int r = 0; r < 4; ++r) {
            const float iv = 1.0f / den[i][r];
            const int l = l0 + lh * 64 + i * 16 + quad * 4 + r;
            const size_t rowbase = ((size_t)b * LL + l) * 1024 + h * 64;
#pragma unroll
            for (int jt = 0; jt < 4; ++jt)
                yb[rowbase + jt * 16 + l15] = (__bf16)(acc[i][jt][r] * iv);
        }
    }
}

extern "C" void kernel_launch(void* const* d_in, const int* in_sizes, int n_in,
                              void* d_out, int out_size, void* d_ws, size_t ws_size,
                              hipStream_t stream) {
    const float* inputs_kv = (const float*)d_in[1];
    const float* Wv = (const float*)d_in[2];   // (D, H*HD)
    const float* bv = (const float*)d_in[3];   // (H*HD)
    const float* r1 = (const float*)d_in[4];   // (H, L, K)
    const float* r2 = (const float*)d_in[5];   // (H, K, L)
    const float* Wo = (const float*)d_in[6];   // (H*HD, D)
    const float* bo = (const float*)d_in[7];   // (D)
    float* out = (float*)d_out;

    char* ws = (char*)d_ws;
    const size_t MB = 1024 * 1024;
    __bf16* A1  = (__bf16*)(ws);             // 16 MB  bf16(inputs_kv) [8192][1024]
    __bf16* Wvt = (__bf16*)(ws + 16 * MB);   //  2 MB  Wv^T
    __bf16* Wot = (__bf16*)(ws + 18 * MB);   //  2 MB  Wo^T
    __bf16* r1b = (__bf16*)(ws + 20 * MB);   //  2 MB  bf16(r1) [h][l][32]
    __bf16* r2t = (__bf16*)(ws + 22 * MB);   //  2 MB  r2^T per head [h][n][32]
    __bf16* V3  = (__bf16*)(ws + 24 * MB);   // 16 MB  V fragment-major (see gemm MODE 0)
    __bf16* yb  = (__bf16*)(ws + 40 * MB);   // 16 MB  y [b][l][h*64+hd]

    prep<<<6144, 256, 0, stream>>>(inputs_kv, r1, Wv, Wo, r2, A1, r1b, Wvt, Wot, r2t);
    gemm_bt<0><<<dim3(8, 64), 256, 0, stream>>>(A1, Wvt, bv, V3, 8192, 1024, 1024);
    attn_pv_v7<<<256, 512, 0, stream>>>(r1b, r2t, V3, yb);
    gemm_bt<1><<<dim3(8, 64), 256, 0, stream>>>(yb, Wot, bo, out, 8192, 1024, 1024);
}

// Round 8
// 201.329 us; speedup vs baseline: 1.1805x; 1.0489x over previous
//
#include <hip/hip_runtime.h>
#include <hip/hip_bf16.h>

// B=4, L=2048, D=1024, H=16, HD=64, K=32, MAXLEN=2048
#define LL 2048

typedef __bf16 bf16x8 __attribute__((ext_vector_type(8)));
typedef __bf16 bf16x4 __attribute__((ext_vector_type(4)));
typedef float f32x4 __attribute__((ext_vector_type(4)));

// async global->LDS, 16B per lane; LDS dest = wave-uniform base + lane*16
__device__ inline void gl_lds16(const __bf16* g, __bf16* l) {
    __builtin_amdgcn_global_load_lds((const __attribute__((address_space(1))) void*)g,
                                     (__attribute__((address_space(3))) void*)l, 16, 0, 0);
}

// ---------------------------------------------------------------------------
// Unified prep: blocks [0,4096) cast inputs_kv->A1; [4096,4608) cast r1->r1b;
// [4608,5120) transpose Wv; [5120,5632) transpose Wo; [5632,6144) transpose r2.
// ---------------------------------------------------------------------------
__global__ __launch_bounds__(256) void prep(const float* __restrict__ inputs_kv,
                                            const float* __restrict__ r1,
                                            const float* __restrict__ Wv,
                                            const float* __restrict__ Wo,
                                            const float* __restrict__ r2,
                                            __bf16* __restrict__ A1,
                                            __bf16* __restrict__ r1b,
                                            __bf16* __restrict__ Wvt,
                                            __bf16* __restrict__ Wot,
                                            __bf16* __restrict__ r2t) {
    __shared__ float Ls[32][65];
    int bid = blockIdx.x;
    const int tid = threadIdx.x;
    if (bid < 4608) {
        const float* in = (bid < 4096) ? inputs_kv : r1;
        __bf16* out = (bid < 4096) ? A1 : r1b;
        const int t = ((bid < 4096) ? bid : bid - 4096) * 256 + tid;
        const float4* in4 = (const float4*)in;
        float4 f0 = in4[t * 2], f1 = in4[t * 2 + 1];
        bf16x8 o;
        o[0] = (__bf16)f0.x; o[1] = (__bf16)f0.y; o[2] = (__bf16)f0.z; o[3] = (__bf16)f0.w;
        o[4] = (__bf16)f1.x; o[5] = (__bf16)f1.y; o[6] = (__bf16)f1.z; o[7] = (__bf16)f1.w;
        *(bf16x8*)&out[(size_t)t * 8] = o;
        return;
    }
    bid -= 4608;
    const float* in;
    __bf16* out;
    int R, C, r0, c0;
    if (bid < 512) {
        in = Wv; out = Wvt; R = 1024; C = 1024;
        c0 = (bid & 15) * 64; r0 = (bid >> 4) * 32;
    } else if (bid < 1024) {
        bid -= 512;
        in = Wo; out = Wot; R = 1024; C = 1024;
        c0 = (bid & 15) * 64; r0 = (bid >> 4) * 32;
    } else {
        bid -= 1024;
        const int bz = bid >> 5;
        in = r2 + (size_t)bz * 65536; out = r2t + (size_t)bz * 65536;
        R = 32; C = 2048;
        c0 = (bid & 31) * 64; r0 = 0;
    }
#pragma unroll
    for (int p = 0; p < 2; ++p) {
        int f = tid + 256 * p;
        int row = f >> 4, c4 = (f & 15) << 2;
        float4 v = *(const float4*)&in[(size_t)(r0 + row) * C + c0 + c4];
        Ls[row][c4 + 0] = v.x; Ls[row][c4 + 1] = v.y;
        Ls[row][c4 + 2] = v.z; Ls[row][c4 + 3] = v.w;
    }
    __syncthreads();
    const int orow = tid >> 2, rc = (tid & 3) << 3;
    bf16x8 o;
#pragma unroll
    for (int j = 0; j < 8; ++j) o[j] = (__bf16)Ls[rc + j][orow];
    *(bf16x8*)&out[(size_t)(c0 + orow) * R + r0 + rc] = o;
}

// ---------------------------------------------------------------------------
// bf16 MFMA GEMM, BK=64. R3/R5/R7 post-mortem: 2-barrier, dbuf and 3-buf
// counted-vmcnt ALL tie (non-attn 160-166us) -> gemm is bound by per-K-step
// fixed overhead (barrier convoy + ds_read latency), paid 32x at BK=32.
// BK=64 halves the step count (16 steps). m132's BK-increase failure mode
// (LDS occupancy cut 3->2 blocks/CU) does NOT apply: we are grid-limited to
// 2 blocks/CU and 2x32KB bufs = 64KB still fits 2 blocks/CU.
// Bank conflicts: 128B rows would make frag reads 4-way conflicted; fixed by
// m173 source-pre-swizzle: staging fetches global chunk ((l&7)^(l>>3)) into
// linear LDS slot (l&7)  [chunk c of row r holds global chunk c^(r&7)], and
// fragment reads XOR their chunk index with (row&7) -> 2 lanes/bank (free).
// Double-buffered, stage(t+1) issued before compute(t), one barrier/step.
// XCD-chunked tile swizzle (T1): per-XCD working set 2MB A-slice + 2MB B.
// MODE 0: scatter bf16 V into FRAGMENT-MAJOR layout V3 (see attn).
// MODE 1: write fp32 C[row][col]
// ---------------------------------------------------------------------------
template <int MODE>
__global__ __launch_bounds__(256) void gemm_bt(const __bf16* __restrict__ A,
                                               const __bf16* __restrict__ Bt,
                                               const float* __restrict__ bias,
                                               void* __restrict__ Cout,
                                               int M, int N, int K) {
    __shared__ alignas(16) __bf16 As[2][128 * 64];   // 16KB each buf
    __shared__ alignas(16) __bf16 Bs[2][128 * 64];   // total 64KB
    const int tid = threadIdx.x;
    const int lane = tid & 63;
    const int wid = __builtin_amdgcn_readfirstlane(tid >> 6);
    // XCD-chunked swizzle: grid is (8,64) -> 512 flat ids
    const int f = blockIdx.y * 8 + blockIdx.x;
    const int g = (f & 7) * 64 + (f >> 3);
    const int row0 = (g >> 3) * 128, col0 = (g & 7) * 128;
    const int l15 = lane & 15, quad = lane >> 4;
    const int wr = wid & 1, wc = wid >> 1;

    // staging geometry: wave wid covers 32 rows [wid*32, wid*32+32) of A and B,
    // 4 calls each (8 rows/call). Lane l -> row +(l>>3), LDS chunk slot (l&7);
    // global src chunk = (l&7)^(l>>3)  (source pre-swizzle, see header).
    const int srow = wid * 32 + (lane >> 3);
    const int skoff = (((lane & 7) ^ (lane >> 3)) << 3);  // bf16 units
    const __bf16* gaS = A + (size_t)(row0 + srow) * K + skoff;
    const __bf16* gbS = Bt + (size_t)(col0 + srow) * K + skoff;
    const int lbase = (wid * 32) * 64;   // LDS bf16 offset of wave's region

    f32x4 acc[4][4];
#pragma unroll
    for (int i = 0; i < 4; ++i)
#pragma unroll
        for (int j = 0; j < 4; ++j) acc[i][j] = (f32x4){0.f, 0.f, 0.f, 0.f};

    const int nt = K >> 6;  // K-steps of 64 (=16)

#define STAGE(buf, k0)                                                        \
    {                                                                         \
        _Pragma("unroll")                                                     \
        for (int q = 0; q < 4; ++q) {                                         \
            gl_lds16(gaS + (size_t)(q * 8) * K + (k0), As[buf] + lbase + q * 512); \
            gl_lds16(gbS + (size_t)(q * 8) * K + (k0), Bs[buf] + lbase + q * 512); \
        }                                                                     \
    }

    // prologue: stage tile 0 into buf 0
    STAGE(0, 0)

    for (int t = 0; t < nt; ++t) {
        __syncthreads();   // buf[t&1] staged (vmcnt drained); prev reads done
        if (t + 1 < nt) {  // stage(t+1) lands during compute(t)
            const int k0 = (t + 1) << 6;
            if ((t & 1) == 0) STAGE(1, k0) else STAGE(0, k0)
        }
        const __bf16* as = As[t & 1];
        const __bf16* bs = Bs[t & 1];
#pragma unroll
        for (int ksub = 0; ksub < 2; ++ksub) {
            bf16x8 af[4], bfv[4];
#pragma unroll
            for (int i = 0; i < 4; ++i) {
                const int r = wr * 64 + i * 16 + l15;
                const int ch = (ksub * 4 + quad) ^ (l15 & 7);
                af[i] = *(const bf16x8*)&as[r * 64 + ch * 8];
            }
#pragma unroll
            for (int j = 0; j < 4; ++j) {
                const int r = wc * 64 + j * 16 + l15;
                const int ch = (ksub * 4 + quad) ^ (l15 & 7);
                bfv[j] = *(const bf16x8*)&bs[r * 64 + ch * 8];
            }
#pragma unroll
            for (int i = 0; i < 4; ++i)
#pragma unroll
                for (int j = 0; j < 4; ++j)
                    acc[i][j] = __builtin_amdgcn_mfma_f32_16x16x32_bf16(af[i], bfv[j], acc[i][j], 0, 0, 0);
        }
    }
#undef STAGE

#pragma unroll
    for (int i = 0; i < 4; ++i) {
        const int rg = row0 + wr * 64 + i * 16 + quad * 4;  // rows rg..rg+3
#pragma unroll
        for (int j = 0; j < 4; ++j) {
            const int cg = col0 + wc * 64 + j * 16 + l15;
            const float bb = bias[cg];
            if (MODE == 0) {
                const int b = rg >> 11, n = rg & 2047;     // 4 consecutive n
                const int h = cg >> 6, hd = cg & 63;
                const int nc = n >> 6, ks = (n >> 5) & 1, qj = (n >> 3) & 3, j0 = n & 7;
                const int jt = hd >> 4, fl = hd & 15;
                __bf16* V3 = (__bf16*)Cout;
                bf16x4 v;
#pragma unroll
                for (int r = 0; r < 4; ++r) v[r] = (__bf16)(acc[i][j][r] + bb);
                *(bf16x4*)&V3[(size_t)(((h * 32 + nc) * 4 + b) * 4096) +
                              (jt * 2 + ks) * 512 + fl * 32 + qj * 8 + j0] = v;
            } else {
                float* Cf = (float*)Cout;
#pragma unroll
                for (int r = 0; r < 4; ++r)
                    Cf[(size_t)(rg + r) * N + cg] = acc[i][j][r] + bb;
            }
        }
    }
}

// ---------------------------------------------------------------------------
// attn v7 (proven 47-48us): 512 thr, 8 waves, 1 block/CU, XOR-swizzled Ps,
// chunk-level software pipeline:
//   lgkmcnt(0); s_barrier (raw: vmcnt NOT drained -> prefetches in flight)
//   pa <- Ps[c&1]; QK(c+1); PV(c); exp(c+1)->Ps[(c+1)&1]; prefetch V,r2.
// v8/v9 post-mortem: 2-blocks/CU launch-bounds variants pinned VGPR to 64 ->
// inner-loop spills -> 76us. Occupancy experiment parked; plain (512) gives
// VGPR 88, no spills.
// ---------------------------------------------------------------------------
__global__ __launch_bounds__(512) void attn_pv_v7(const __bf16* __restrict__ r1b,
                                                  const __bf16* __restrict__ r2t,
                                                  const __bf16* __restrict__ V3,
                                                  __bf16* __restrict__ yb) {
    __shared__ alignas(16) __bf16 Ps[2 * 2 * 4 * 1024];   // [buf][lh][i][ks*512+...] 32KB
    const int tid = threadIdx.x;
    const int lane = tid & 63;
    const int w = __builtin_amdgcn_readfirstlane(tid >> 6);
    const int b = w & 3, lh = w >> 2;
    const int l15 = lane & 15, quad = lane >> 4;
    const int id = blockIdx.x;
    const int h = id & 15;             // id%8 == h%8 -> per-XCD head locality
    const int l0 = (id >> 4) << 7;

    // r1 B-frags for this wave's 64 l (fixed)
    bf16x8 bf1[4];
#pragma unroll
    for (int i = 0; i < 4; ++i)
        bf1[i] = *(const bf16x8*)&r1b[(size_t)(h * 2048 + l0 + lh * 64 + i * 16 + l15) * 32 + quad * 8];

    const __bf16* r2p = r2t + (size_t)(h * 2048 + b * 16 + l15) * 32 + quad * 8;
    const __bf16* vp = V3 + (size_t)((h * 32) * 4 + b) * 4096 + l15 * 32 + quad * 8;

    // chunk-0 prefetch
    bf16x8 r2f = *(const bf16x8*)r2p;
    bf16x8 vpf[4][2];
#pragma unroll
    for (int jt = 0; jt < 4; ++jt)
#pragma unroll
        for (int ks = 0; ks < 2; ++ks)
            vpf[jt][ks] = *(const bf16x8*)(vp + (jt * 2 + ks) * 512);

    bf16x8 ones;
#pragma unroll
    for (int e = 0; e < 8; ++e) ones[e] = (__bf16)1.0f;

    f32x4 acc[4][4];
    f32x4 den[4];
#pragma unroll
    for (int i = 0; i < 4; ++i) {
        den[i] = (f32x4){0.f, 0.f, 0.f, 0.f};
#pragma unroll
        for (int j = 0; j < 4; ++j) acc[i][j] = (f32x4){0.f, 0.f, 0.f, 0.f};
    }
    const f32x4 zero4 = {0.f, 0.f, 0.f, 0.f};

    const int kw = b >> 1;                       // which ks this wave produces
    const int jg = (b & 1) * 2 + (quad >> 1);    // j-group within frag
    const int q4 = (quad & 1) * 4;
    const int swz = (l15 >> 1) & 3;              // bank swizzle for Ps slots

    // ---- prologue: QK(0) -> exp -> write Ps[0]; prefetch r2f(1)
    f32x4 s[4];
#pragma unroll
    for (int i = 0; i < 4; ++i)
        s[i] = __builtin_amdgcn_mfma_f32_16x16x32_bf16(r2f, bf1[i], zero4, 0, 0, 0);
    r2f = *(const bf16x8*)(r2p + 2048);
    {
        __bf16* ps = &Ps[lh * 4096];
#pragma unroll
        for (int i = 0; i < 4; ++i) {
            bf16x4 p4;
#pragma unroll
            for (int r = 0; r < 4; ++r) p4[r] = (__bf16)__expf(s[i][r]);
            *(bf16x4*)&ps[i * 1024 + kw * 512 + l15 * 32 + ((jg ^ swz) << 3) + q4] = p4;
        }
    }

    for (int c = 0; c < 32; ++c) {
        asm volatile("s_waitcnt lgkmcnt(0)" ::: "memory");
        __builtin_amdgcn_s_barrier();
        const __bf16* ps_r = &Ps[((c & 1) * 2 + lh) * 4096];
        bf16x8 pa[4][2];
#pragma unroll
        for (int i = 0; i < 4; ++i)
#pragma unroll
            for (int ks = 0; ks < 2; ++ks)
                pa[i][ks] = *(const bf16x8*)&ps_r[i * 1024 + ks * 512 + l15 * 32 + ((quad ^ swz) << 3)];
        // QK(c+1): at c=31 this recomputes chunk 31 into a dead buffer
#pragma unroll
        for (int i = 0; i < 4; ++i)
            s[i] = __builtin_amdgcn_mfma_f32_16x16x32_bf16(r2f, bf1[i], zero4, 0, 0, 0);
        const int i2 = (c < 30) ? (c + 2) : 31;
        r2f = *(const bf16x8*)(r2p + (size_t)i2 * 2048);
        // PV(c) + denominators (consume pa, vpf)
#pragma unroll
        for (int ks = 0; ks < 2; ++ks) {
#pragma unroll
            for (int i = 0; i < 4; ++i) {
#pragma unroll
                for (int jt = 0; jt < 4; ++jt)
                    acc[i][jt] = __builtin_amdgcn_mfma_f32_16x16x32_bf16(pa[i][ks], vpf[jt][ks],
                                                                         acc[i][jt], 0, 0, 0);
                den[i] = __builtin_amdgcn_mfma_f32_16x16x32_bf16(pa[i][ks], ones, den[i], 0, 0, 0);
            }
        }
        // exp(c+1) + write Ps[(c+1)&1] — VALU, overlaps PV MFMA issue
        __bf16* ps_w = &Ps[(((c + 1) & 1) * 2 + lh) * 4096];
#pragma unroll
        for (int i = 0; i < 4; ++i) {
            bf16x4 p4;
#pragma unroll
            for (int r = 0; r < 4; ++r) p4[r] = (__bf16)__expf(s[i][r]);
            *(bf16x4*)&ps_w[i * 1024 + kw * 512 + l15 * 32 + ((jg ^ swz) << 3) + q4] = p4;
        }
        // V prefetch for chunk c+1 (stays in flight across next barrier)
        const int cv = (c < 31) ? 1 : 0;
        vp += cv * 16384;
#pragma unroll
        for (int jt = 0; jt < 4; ++jt)
#pragma unroll
            for (int ks = 0; ks < 2; ++ks)
                vpf[jt][ks] = *(const bf16x8*)(vp + (jt * 2 + ks) * 512);
    }

    // epilogue: den[i][r] is the softmax denom for l = lh*64+i*16+quad*4+r (per-lane!)
#pragma unroll
    for (int i = 0; i < 4; ++i) {
#pragma unroll
        for (int r = 0; r < 4; ++r) {
            const float iv = 1.0f / den[i][r];
            const int l = l0 + lh * 64 + i * 16 + quad * 4 + r;
            const size_t rowbase = ((size_t)b * LL + l) * 1024 + h * 64;
#pragma unroll
            for (int jt = 0; jt < 4; ++jt)
                yb[rowbase + jt * 16 + l15] = (__bf16)(acc[i][jt][r] * iv);
        }
    }
}

extern "C" void kernel_launch(void* const* d_in, const int* in_sizes, int n_in,
                              void* d_out, int out_size, void* d_ws, size_t ws_size,
                              hipStream_t stream) {
    const float* inputs_kv = (const float*)d_in[1];
    const float* Wv = (const float*)d_in[2];   // (D, H*HD)
    const float* bv = (const float*)d_in[3];   // (H*HD)
    const float* r1 = (const float*)d_in[4];   // (H, L, K)
    const float* r2 = (const float*)d_in[5];   // (H, K, L)
    const float* Wo = (const float*)d_in[6];   // (H*HD, D)
    const float* bo = (const float*)d_in[7];   // (D)
    float* out = (float*)d_out;

    char* ws = (char*)d_ws;
    const size_t MB = 1024 * 1024;
    __bf16* A1  = (__bf16*)(ws);             // 16 MB  bf16(inputs_kv) [8192][1024]
    __bf16* Wvt = (__bf16*)(ws + 16 * MB);   //  2 MB  Wv^T
    __bf16* Wot = (__bf16*)(ws + 18 * MB);   //  2 MB  Wo^T
    __bf16* r1b = (__bf16*)(ws + 20 * MB);   //  2 MB  bf16(r1) [h][l][32]
    __bf16* r2t = (__bf16*)(ws + 22 * MB);   //  2 MB  r2^T per head [h][n][32]
    __bf16* V3  = (__bf16*)(ws + 24 * MB);   // 16 MB  V fragment-major (see gemm MODE 0)
    __bf16* yb  = (__bf16*)(ws + 40 * MB);   // 16 MB  y [b][l][h*64+hd]

    prep<<<6144, 256, 0, stream>>>(inputs_kv, r1, Wv, Wo, r2, A1, r1b, Wvt, Wot, r2t);
    gemm_bt<0><<<dim3(8, 64), 256, 0, stream>>>(A1, Wvt, bv, V3, 8192, 1024, 1024);
    attn_pv_v7<<<256, 512, 0, stream>>>(r1b, r2t, V3, yb);
    gemm_bt<1><<<dim3(8, 64), 256, 0, stream>>>(yb, Wot, bo, out, 8192, 1024, 1024);
}

// Round 9
// 198.463 us; speedup vs baseline: 1.1976x; 1.0144x over previous
//
#include <hip/hip_runtime.h>
#include <hip/hip_bf16.h>

// B=4, L=2048, D=1024, H=16, HD=64, K=32, MAXLEN=2048
#define LL 2048

typedef __bf16 bf16x8 __attribute__((ext_vector_type(8)));
typedef __bf16 bf16x4 __attribute__((ext_vector_type(4)));
typedef float f32x4 __attribute__((ext_vector_type(4)));

// async global->LDS, 16B per lane; LDS dest = wave-uniform base + lane*16
__device__ inline void gl_lds16(const __bf16* g, __bf16* l) {
    __builtin_amdgcn_global_load_lds((const __attribute__((address_space(1))) void*)g,
                                     (__attribute__((address_space(3))) void*)l, 16, 0, 0);
}

// ---------------------------------------------------------------------------
// Unified prep: blocks [0,4096) cast inputs_kv->A1; [4096,4608) cast r1->r1b;
// [4608,5120) transpose Wv; [5120,5632) transpose Wo; [5632,6144) transpose r2.
// ---------------------------------------------------------------------------
__global__ __launch_bounds__(256) void prep(const float* __restrict__ inputs_kv,
                                            const float* __restrict__ r1,
                                            const float* __restrict__ Wv,
                                            const float* __restrict__ Wo,
                                            const float* __restrict__ r2,
                                            __bf16* __restrict__ A1,
                                            __bf16* __restrict__ r1b,
                                            __bf16* __restrict__ Wvt,
                                            __bf16* __restrict__ Wot,
                                            __bf16* __restrict__ r2t) {
    __shared__ float Ls[32][65];
    int bid = blockIdx.x;
    const int tid = threadIdx.x;
    if (bid < 4608) {
        const float* in = (bid < 4096) ? inputs_kv : r1;
        __bf16* out = (bid < 4096) ? A1 : r1b;
        const int t = ((bid < 4096) ? bid : bid - 4096) * 256 + tid;
        const float4* in4 = (const float4*)in;
        float4 f0 = in4[t * 2], f1 = in4[t * 2 + 1];
        bf16x8 o;
        o[0] = (__bf16)f0.x; o[1] = (__bf16)f0.y; o[2] = (__bf16)f0.z; o[3] = (__bf16)f0.w;
        o[4] = (__bf16)f1.x; o[5] = (__bf16)f1.y; o[6] = (__bf16)f1.z; o[7] = (__bf16)f1.w;
        *(bf16x8*)&out[(size_t)t * 8] = o;
        return;
    }
    bid -= 4608;
    const float* in;
    __bf16* out;
    int R, C, r0, c0;
    if (bid < 512) {
        in = Wv; out = Wvt; R = 1024; C = 1024;
        c0 = (bid & 15) * 64; r0 = (bid >> 4) * 32;
    } else if (bid < 1024) {
        bid -= 512;
        in = Wo; out = Wot; R = 1024; C = 1024;
        c0 = (bid & 15) * 64; r0 = (bid >> 4) * 32;
    } else {
        bid -= 1024;
        const int bz = bid >> 5;
        in = r2 + (size_t)bz * 65536; out = r2t + (size_t)bz * 65536;
        R = 32; C = 2048;
        c0 = (bid & 31) * 64; r0 = 0;
    }
#pragma unroll
    for (int p = 0; p < 2; ++p) {
        int f = tid + 256 * p;
        int row = f >> 4, c4 = (f & 15) << 2;
        float4 v = *(const float4*)&in[(size_t)(r0 + row) * C + c0 + c4];
        Ls[row][c4 + 0] = v.x; Ls[row][c4 + 1] = v.y;
        Ls[row][c4 + 2] = v.z; Ls[row][c4 + 3] = v.w;
    }
    __syncthreads();
    const int orow = tid >> 2, rc = (tid & 3) << 3;
    bf16x8 o;
#pragma unroll
    for (int j = 0; j < 8; ++j) o[j] = (__bf16)Ls[rc + j][orow];
    *(bf16x8*)&out[(size_t)(c0 + orow) * R + r0 + rc] = o;
}

// ---------------------------------------------------------------------------
// bf16 MFMA GEMM, BK=64, 512 THREADS (8 waves). R8 arithmetic: per-CU LDS
// traffic/step ~1536cyc vs measured ~5700cyc/step -> LDS only ~25% utilized,
// gemm still exposed-latency bound. Occupancy is LDS-limited to 2 blocks/CU
// (64KB/block) REGARDLESS of block size -> 512-thread blocks double resident
// waves to 16/CU (4/SIMD) at zero LDS cost. (v8/v9 lesson: no second
// launch_bounds arg — attn's plain (512) yields 88 VGPR; live state here ~80.)
// Wave layout 2x4: wave owns 64x32 (acc[4][2]); af dup raises LDS reads
// 64->96KB/block-step — affordable at 25% util.
// Bank-conflict-free via m173 source-pre-swizzle (see R8): LDS row r chunk
// slot c holds global chunk c^(r&7); reads XOR chunk with (row&7).
// Double-buffered, stage(t+1) before compute(t), one barrier/step.
// XCD-chunked tile swizzle (T1): per-XCD working set 2MB A-slice + 2MB B.
// MODE 0: scatter bf16 V into FRAGMENT-MAJOR layout V3 (see attn).
// MODE 1: write fp32 C[row][col]
// ---------------------------------------------------------------------------
template <int MODE>
__global__ __launch_bounds__(512) void gemm_bt(const __bf16* __restrict__ A,
                                               const __bf16* __restrict__ Bt,
                                               const float* __restrict__ bias,
                                               void* __restrict__ Cout,
                                               int M, int N, int K) {
    __shared__ alignas(16) __bf16 As[2][128 * 64];   // 16KB each buf
    __shared__ alignas(16) __bf16 Bs[2][128 * 64];   // total 64KB
    const int tid = threadIdx.x;
    const int lane = tid & 63;
    const int wid = __builtin_amdgcn_readfirstlane(tid >> 6);
    // XCD-chunked swizzle: grid is (8,64) -> 512 flat ids
    const int f = blockIdx.y * 8 + blockIdx.x;
    const int g = (f & 7) * 64 + (f >> 3);
    const int row0 = (g >> 3) * 128, col0 = (g & 7) * 128;
    const int l15 = lane & 15, quad = lane >> 4;
    const int wr = wid & 1, wc = wid >> 1;   // 2 x 4 wave grid, wave tile 64x32

    // staging geometry: wave wid covers 16 rows [wid*16, wid*16+16) of A and B,
    // 2 calls each (8 rows/call). Lane l -> row +(l>>3), LDS chunk slot (l&7);
    // global src chunk = (l&7)^(l>>3)  (source pre-swizzle, see header).
    const int srow = wid * 16 + (lane >> 3);
    const int skoff = (((lane & 7) ^ (lane >> 3)) << 3);  // bf16 units
    const __bf16* gaS = A + (size_t)(row0 + srow) * K + skoff;
    const __bf16* gbS = Bt + (size_t)(col0 + srow) * K + skoff;
    const int lbase = (wid * 16) * 64;   // LDS bf16 offset of wave's region

    f32x4 acc[4][2];
#pragma unroll
    for (int i = 0; i < 4; ++i)
#pragma unroll
        for (int j = 0; j < 2; ++j) acc[i][j] = (f32x4){0.f, 0.f, 0.f, 0.f};

    const int nt = K >> 6;  // K-steps of 64 (=16)

#define STAGE(buf, k0)                                                        \
    {                                                                         \
        _Pragma("unroll")                                                     \
        for (int q = 0; q < 2; ++q) {                                         \
            gl_lds16(gaS + (size_t)(q * 8) * K + (k0), As[buf] + lbase + q * 512); \
            gl_lds16(gbS + (size_t)(q * 8) * K + (k0), Bs[buf] + lbase + q * 512); \
        }                                                                     \
    }

    // prologue: stage tile 0 into buf 0
    STAGE(0, 0)

    for (int t = 0; t < nt; ++t) {
        __syncthreads();   // buf[t&1] staged (vmcnt drained); prev reads done
        if (t + 1 < nt) {  // stage(t+1) lands during compute(t)
            const int k0 = (t + 1) << 6;
            if ((t & 1) == 0) STAGE(1, k0) else STAGE(0, k0)
        }
        const __bf16* as = As[t & 1];
        const __bf16* bs = Bs[t & 1];
#pragma unroll
        for (int ksub = 0; ksub < 2; ++ksub) {
            bf16x8 af[4], bfv[2];
            const int ch = ((ksub * 4 + quad) ^ (l15 & 7)) * 8;
#pragma unroll
            for (int i = 0; i < 4; ++i) {
                const int r = wr * 64 + i * 16 + l15;
                af[i] = *(const bf16x8*)&as[r * 64 + ch];
            }
#pragma unroll
            for (int j = 0; j < 2; ++j) {
                const int r = wc * 32 + j * 16 + l15;
                bfv[j] = *(const bf16x8*)&bs[r * 64 + ch];
            }
#pragma unroll
            for (int i = 0; i < 4; ++i)
#pragma unroll
                for (int j = 0; j < 2; ++j)
                    acc[i][j] = __builtin_amdgcn_mfma_f32_16x16x32_bf16(af[i], bfv[j], acc[i][j], 0, 0, 0);
        }
    }
#undef STAGE

#pragma unroll
    for (int i = 0; i < 4; ++i) {
        const int rg = row0 + wr * 64 + i * 16 + quad * 4;  // rows rg..rg+3
#pragma unroll
        for (int j = 0; j < 2; ++j) {
            const int cg = col0 + wc * 32 + j * 16 + l15;
            const float bb = bias[cg];
            if (MODE == 0) {
                const int b = rg >> 11, n = rg & 2047;     // 4 consecutive n
                const int h = cg >> 6, hd = cg & 63;
                const int nc = n >> 6, ks = (n >> 5) & 1, qj = (n >> 3) & 3, j0 = n & 7;
                const int jt = hd >> 4, fl = hd & 15;
                __bf16* V3 = (__bf16*)Cout;
                bf16x4 v;
#pragma unroll
                for (int r = 0; r < 4; ++r) v[r] = (__bf16)(acc[i][j][r] + bb);
                *(bf16x4*)&V3[(size_t)(((h * 32 + nc) * 4 + b) * 4096) +
                              (jt * 2 + ks) * 512 + fl * 32 + qj * 8 + j0] = v;
            } else {
                float* Cf = (float*)Cout;
#pragma unroll
                for (int r = 0; r < 4; ++r)
                    Cf[(size_t)(rg + r) * N + cg] = acc[i][j][r] + bb;
            }
        }
    }
}

// ---------------------------------------------------------------------------
// attn v7 (proven 46.5-48us): 512 thr, 8 waves, 1 block/CU, XOR-swizzled Ps,
// chunk-level software pipeline:
//   lgkmcnt(0); s_barrier (raw: vmcnt NOT drained -> prefetches in flight)
//   pa <- Ps[c&1]; QK(c+1); PV(c); exp(c+1)->Ps[(c+1)&1]; prefetch V,r2.
// v8/v9 post-mortem: 2-blocks/CU launch-bounds variants pinned VGPR to 64 ->
// inner-loop spills -> 76us. Occupancy experiment parked; plain (512) gives
// VGPR 88, no spills.
// ---------------------------------------------------------------------------
__global__ __launch_bounds__(512) void attn_pv_v7(const __bf16* __restrict__ r1b,
                                                  const __bf16* __restrict__ r2t,
                                                  const __bf16* __restrict__ V3,
                                                  __bf16* __restrict__ yb) {
    __shared__ alignas(16) __bf16 Ps[2 * 2 * 4 * 1024];   // [buf][lh][i][ks*512+...] 32KB
    const int tid = threadIdx.x;
    const int lane = tid & 63;
    const int w = __builtin_amdgcn_readfirstlane(tid >> 6);
    const int b = w & 3, lh = w >> 2;
    const int l15 = lane & 15, quad = lane >> 4;
    const int id = blockIdx.x;
    const int h = id & 15;             // id%8 == h%8 -> per-XCD head locality
    const int l0 = (id >> 4) << 7;

    // r1 B-frags for this wave's 64 l (fixed)
    bf16x8 bf1[4];
#pragma unroll
    for (int i = 0; i < 4; ++i)
        bf1[i] = *(const bf16x8*)&r1b[(size_t)(h * 2048 + l0 + lh * 64 + i * 16 + l15) * 32 + quad * 8];

    const __bf16* r2p = r2t + (size_t)(h * 2048 + b * 16 + l15) * 32 + quad * 8;
    const __bf16* vp = V3 + (size_t)((h * 32) * 4 + b) * 4096 + l15 * 32 + quad * 8;

    // chunk-0 prefetch
    bf16x8 r2f = *(const bf16x8*)r2p;
    bf16x8 vpf[4][2];
#pragma unroll
    for (int jt = 0; jt < 4; ++jt)
#pragma unroll
        for (int ks = 0; ks < 2; ++ks)
            vpf[jt][ks] = *(const bf16x8*)(vp + (jt * 2 + ks) * 512);

    bf16x8 ones;
#pragma unroll
    for (int e = 0; e < 8; ++e) ones[e] = (__bf16)1.0f;

    f32x4 acc[4][4];
    f32x4 den[4];
#pragma unroll
    for (int i = 0; i < 4; ++i) {
        den[i] = (f32x4){0.f, 0.f, 0.f, 0.f};
#pragma unroll
        for (int j = 0; j < 4; ++j) acc[i][j] = (f32x4){0.f, 0.f, 0.f, 0.f};
    }
    const f32x4 zero4 = {0.f, 0.f, 0.f, 0.f};

    const int kw = b >> 1;                       // which ks this wave produces
    const int jg = (b & 1) * 2 + (quad >> 1);    // j-group within frag
    const int q4 = (quad & 1) * 4;
    const int swz = (l15 >> 1) & 3;              // bank swizzle for Ps slots

    // ---- prologue: QK(0) -> exp -> write Ps[0]; prefetch r2f(1)
    f32x4 s[4];
#pragma unroll
    for (int i = 0; i < 4; ++i)
        s[i] = __builtin_amdgcn_mfma_f32_16x16x32_bf16(r2f, bf1[i], zero4, 0, 0, 0);
    r2f = *(const bf16x8*)(r2p + 2048);
    {
        __bf16* ps = &Ps[lh * 4096];
#pragma unroll
        for (int i = 0; i < 4; ++i) {
            bf16x4 p4;
#pragma unroll
            for (int r = 0; r < 4; ++r) p4[r] = (__bf16)__expf(s[i][r]);
            *(bf16x4*)&ps[i * 1024 + kw * 512 + l15 * 32 + ((jg ^ swz) << 3) + q4] = p4;
        }
    }

    for (int c = 0; c < 32; ++c) {
        asm volatile("s_waitcnt lgkmcnt(0)" ::: "memory");
        __builtin_amdgcn_s_barrier();
        const __bf16* ps_r = &Ps[((c & 1) * 2 + lh) * 4096];
        bf16x8 pa[4][2];
#pragma unroll
        for (int i = 0; i < 4; ++i)
#pragma unroll
            for (int ks = 0; ks < 2; ++ks)
                pa[i][ks] = *(const bf16x8*)&ps_r[i * 1024 + ks * 512 + l15 * 32 + ((quad ^ swz) << 3)];
        // QK(c+1): at c=31 this recomputes chunk 31 into a dead buffer
#pragma unroll
        for (int i = 0; i < 4; ++i)
            s[i] = __builtin_amdgcn_mfma_f32_16x16x32_bf16(r2f, bf1[i], zero4, 0, 0, 0);
        const int i2 = (c < 30) ? (c + 2) : 31;
        r2f = *(const bf16x8*)(r2p + (size_t)i2 * 2048);
        // PV(c) + denominators (consume pa, vpf)
#pragma unroll
        for (int ks = 0; ks < 2; ++ks) {
#pragma unroll
            for (int i = 0; i < 4; ++i) {
#pragma unroll
                for (int jt = 0; jt < 4; ++jt)
                    acc[i][jt] = __builtin_amdgcn_mfma_f32_16x16x32_bf16(pa[i][ks], vpf[jt][ks],
                                                                         acc[i][jt], 0, 0, 0);
                den[i] = __builtin_amdgcn_mfma_f32_16x16x32_bf16(pa[i][ks], ones, den[i], 0, 0, 0);
            }
        }
        // exp(c+1) + write Ps[(c+1)&1] — VALU, overlaps PV MFMA issue
        __bf16* ps_w = &Ps[(((c + 1) & 1) * 2 + lh) * 4096];
#pragma unroll
        for (int i = 0; i < 4; ++i) {
            bf16x4 p4;
#pragma unroll
            for (int r = 0; r < 4; ++r) p4[r] = (__bf16)__expf(s[i][r]);
            *(bf16x4*)&ps_w[i * 1024 + kw * 512 + l15 * 32 + ((jg ^ swz) << 3) + q4] = p4;
        }
        // V prefetch for chunk c+1 (stays in flight across next barrier)
        const int cv = (c < 31) ? 1 : 0;
        vp += cv * 16384;
#pragma unroll
        for (int jt = 0; jt < 4; ++jt)
#pragma unroll
            for (int ks = 0; ks < 2; ++ks)
                vpf[jt][ks] = *(const bf16x8*)(vp + (jt * 2 + ks) * 512);
    }

    // epilogue: den[i][r] is the softmax denom for l = lh*64+i*16+quad*4+r (per-lane!)
#pragma unroll
    for (int i = 0; i < 4; ++i) {
#pragma unroll
        for (int r = 0; r < 4; ++r) {
            const float iv = 1.0f / den[i][r];
            const int l = l0 + lh * 64 + i * 16 + quad * 4 + r;
            const size_t rowbase = ((size_t)b * LL + l) * 1024 + h * 64;
#pragma unroll
            for (int jt = 0; jt < 4; ++jt)
                yb[rowbase + jt * 16 + l15] = (__bf16)(acc[i][jt][r] * iv);
        }
    }
}

extern "C" void kernel_launch(void* const* d_in, const int* in_sizes, int n_in,
                              void* d_out, int out_size, void* d_ws, size_t ws_size,
                              hipStream_t stream) {
    const float* inputs_kv = (const float*)d_in[1];
    const float* Wv = (const float*)d_in[2];   // (D, H*HD)
    const float* bv = (const float*)d_in[3];   // (H*HD)
    const float* r1 = (const float*)d_in[4];   // (H, L, K)
    const float* r2 = (const float*)d_in[5];   // (H, K, L)
    const float* Wo = (const float*)d_in[6];   // (H*HD, D)
    const float* bo = (const float*)d_in[7];   // (D)
    float* out = (float*)d_out;

    char* ws = (char*)d_ws;
    const size_t MB = 1024 * 1024;
    __bf16* A1  = (__bf16*)(ws);             // 16 MB  bf16(inputs_kv) [8192][1024]
    __bf16* Wvt = (__bf16*)(ws + 16 * MB);   //  2 MB  Wv^T
    __bf16* Wot = (__bf16*)(ws + 18 * MB);   //  2 MB  Wo^T
    __bf16* r1b = (__bf16*)(ws + 20 * MB);   //  2 MB  bf16(r1) [h][l][32]
    __bf16* r2t = (__bf16*)(ws + 22 * MB);   //  2 MB  r2^T per head [h][n][32]
    __bf16* V3  = (__bf16*)(ws + 24 * MB);   // 16 MB  V fragment-major (see gemm MODE 0)
    __bf16* yb  = (__bf16*)(ws + 40 * MB);   // 16 MB  y [b][l][h*64+hd]

    prep<<<6144, 256, 0, stream>>>(inputs_kv, r1, Wv, Wo, r2, A1, r1b, Wvt, Wot, r2t);
    gemm_bt<0><<<dim3(8, 64), 512, 0, stream>>>(A1, Wvt, bv, V3, 8192, 1024, 1024);
    attn_pv_v7<<<256, 512, 0, stream>>>(r1b, r2t, V3, yb);
    gemm_bt<1><<<dim3(8, 64), 512, 0, stream>>>(yb, Wot, bo, out, 8192, 1024, 1024);
}